// Round 1
// baseline (1899.861 us; speedup 1.0000x reference)
//
#include <hip/hip_runtime.h>
#include <hip/hip_bf16.h>

typedef __attribute__((ext_vector_type(8))) short short8;
typedef __attribute__((ext_vector_type(4))) float f32x4;

__device__ __forceinline__ float bf2f(unsigned short u) {
    union { unsigned int i; float f; } c;
    c.i = ((unsigned int)u) << 16;
    return c.f;
}
__device__ __forceinline__ unsigned short f2bf(float f) {
    union { float f; unsigned int i; } c;
    c.f = f;
    unsigned int x = c.i;
    x += 0x7FFFu + ((x >> 16) & 1u);
    return (unsigned short)(x >> 16);
}

// ---------------- GEMM: C[n,M] = A[n,K] @ W[K,M] + bias, bf16 MFMA ----------
// Wp is W pre-transposed to [M][K] bf16 (so B-fragments are contiguous).
// Also accumulates per-column sum / sumsq of (A@W+bias) over valid rows.
template<int K, bool AF32>
__global__ __launch_bounds__(256)
void gemm_kernel(const void* __restrict__ Av,
                 const unsigned short* __restrict__ Wp,
                 const float* __restrict__ bias,
                 float* __restrict__ ssum,
                 float* __restrict__ ssq,
                 unsigned short* __restrict__ C,
                 int nrows, int M)
{
    const int tid  = threadIdx.x;
    const int lane = tid & 63;
    const int wave = tid >> 6;
    const int wr = wave >> 1, wc = wave & 1;  // 2x2 waves, each 32x32
    const int lrow = lane & 15;
    const int kg   = lane >> 4;               // 0..3
    const int row0 = blockIdx.x * 64 + wr * 32;
    const int col0 = blockIdx.y * 64 + wc * 32;

    f32x4 acc00 = {0.f, 0.f, 0.f, 0.f};
    f32x4 acc01 = acc00, acc10 = acc00, acc11 = acc00;

    const int r0 = row0 + lrow;
    const int r1 = r0 + 16;
    const int r0c = r0 < nrows ? r0 : nrows - 1;   // clamp: loads stay in-bounds
    const int r1c = r1 < nrows ? r1 : nrows - 1;

    const unsigned short* w0p = Wp + (size_t)(col0 + lrow) * K + kg * 8;
    const unsigned short* w1p = w0p + (size_t)16 * K;

    #pragma unroll 4
    for (int k0 = 0; k0 < K; k0 += 32) {
        short8 a0, a1;
        if (AF32) {
            const float* A = (const float*)Av;
            const float* p0 = A + (size_t)r0c * K + k0 + kg * 8;
            const float* p1 = A + (size_t)r1c * K + k0 + kg * 8;
            f32x4 u0 = *(const f32x4*)p0;
            f32x4 u1 = *(const f32x4*)(p0 + 4);
            f32x4 v0 = *(const f32x4*)p1;
            f32x4 v1 = *(const f32x4*)(p1 + 4);
            #pragma unroll
            for (int j = 0; j < 4; ++j) {
                a0[j]     = (short)f2bf(u0[j]);
                a0[j + 4] = (short)f2bf(u1[j]);
                a1[j]     = (short)f2bf(v0[j]);
                a1[j + 4] = (short)f2bf(v1[j]);
            }
        } else {
            const unsigned short* A = (const unsigned short*)Av;
            a0 = *(const short8*)(A + (size_t)r0c * K + k0 + kg * 8);
            a1 = *(const short8*)(A + (size_t)r1c * K + k0 + kg * 8);
        }
        short8 b0 = *(const short8*)(w0p + k0);
        short8 b1 = *(const short8*)(w1p + k0);
        acc00 = __builtin_amdgcn_mfma_f32_16x16x32_bf16(a0, b0, acc00, 0, 0, 0);
        acc01 = __builtin_amdgcn_mfma_f32_16x16x32_bf16(a0, b1, acc01, 0, 0, 0);
        acc10 = __builtin_amdgcn_mfma_f32_16x16x32_bf16(a1, b0, acc10, 0, 0, 0);
        acc11 = __builtin_amdgcn_mfma_f32_16x16x32_bf16(a1, b1, acc11, 0, 0, 0);
    }

    // Epilogue: bias, bf16 store, per-column stats.
    // C/D layout (verified): col = lane&15, row = (lane>>4)*4 + i
    #pragma unroll
    for (int c = 0; c < 2; ++c) {
        const int col = col0 + c * 16 + lrow;
        const float bc = bias[col];
        float s = 0.f, q = 0.f;
        #pragma unroll
        for (int r = 0; r < 2; ++r) {
            f32x4 av;
            if (r == 0) av = c ? acc01 : acc00;
            else        av = c ? acc11 : acc10;
            const int rb = row0 + r * 16 + kg * 4;
            #pragma unroll
            for (int i = 0; i < 4; ++i) {
                const int row = rb + i;
                if (row < nrows) {
                    const float v = av[i] + bc;
                    C[(size_t)row * M + col] = f2bf(v);
                    s += v;
                    q += v * v;
                }
            }
        }
        s += __shfl_xor(s, 16); s += __shfl_xor(s, 32);
        q += __shfl_xor(q, 16); q += __shfl_xor(q, 32);
        if (kg == 0) {
            atomicAdd(&ssum[col], s);
            atomicAdd(&ssq[col], q);
        }
    }
}

// ---------------- elementwise: BN(+GELU)(+residuals), bf16/f32 outputs ------
__global__ void ew_kernel(const unsigned short* __restrict__ xin,
                          const float* __restrict__ ssum,
                          const float* __restrict__ ssq,
                          const float* __restrict__ gam,
                          const float* __restrict__ bet,
                          float invN, int do_gelu,
                          const unsigned short* __restrict__ res1,
                          const float* __restrict__ res2,
                          unsigned short* __restrict__ outb,
                          float* __restrict__ outf,
                          int total4, int cmask)
{
    int idx = blockIdx.x * blockDim.x + threadIdx.x;
    if (idx >= total4) return;
    const int base = idx * 4;
    const int c0 = base & cmask;

    ushort4 xv = *(const ushort4*)(xin + base);
    unsigned short xs[4] = {xv.x, xv.y, xv.z, xv.w};
    float r1[4] = {0.f, 0.f, 0.f, 0.f};
    float r2[4] = {0.f, 0.f, 0.f, 0.f};
    if (res1) {
        ushort4 rv = *(const ushort4*)(res1 + base);
        r1[0] = bf2f(rv.x); r1[1] = bf2f(rv.y); r1[2] = bf2f(rv.z); r1[3] = bf2f(rv.w);
    }
    if (res2) {
        float4 rv = *(const float4*)(res2 + base);
        r2[0] = rv.x; r2[1] = rv.y; r2[2] = rv.z; r2[3] = rv.w;
    }

    float o[4];
    #pragma unroll
    for (int j = 0; j < 4; ++j) {
        const int c = c0 + j;
        const float mean = ssum[c] * invN;
        const float var  = ssq[c] * invN - mean * mean;
        const float sc = gam[c] * rsqrtf(var + 1e-5f);
        const float sh = bet[c] - mean * sc;
        float v = sc * bf2f(xs[j]) + sh;
        if (do_gelu) v = 0.5f * v * (1.0f + erff(v * 0.70710678118f));
        o[j] = v + r1[j] + r2[j];
    }
    if (outb) {
        ushort4 ov;
        ov.x = f2bf(o[0]); ov.y = f2bf(o[1]); ov.z = f2bf(o[2]); ov.w = f2bf(o[3]);
        *(ushort4*)(outb + base) = ov;
    }
    if (outf) {
        float4 ov;
        ov.x = o[0]; ov.y = o[1]; ov.z = o[2]; ov.w = o[3];
        *(float4*)(outf + base) = ov;
    }
}

// ---------------- GIN scatter-add: Z[dst] += H[src] -------------------------
__global__ void scatter_kernel(const int* __restrict__ ei,
                               const unsigned short* __restrict__ H,
                               float* __restrict__ Z, int E)
{
    const long long gid = (long long)blockIdx.x * blockDim.x + threadIdx.x;
    const int e = (int)(gid >> 5);
    if (e >= E) return;
    const int g4 = ((int)gid & 31) * 4;
    const int src = ei[e];
    const int dst = ei[E + e];
    ushort4 h = *(const ushort4*)(H + (size_t)src * 128 + g4);
    float* zp = Z + (size_t)dst * 128 + g4;
    atomicAdd(zp + 0, bf2f(h.x));
    atomicAdd(zp + 1, bf2f(h.y));
    atomicAdd(zp + 2, bf2f(h.z));
    atomicAdd(zp + 3, bf2f(h.w));
}

// ---------------- weight pack: Wp[m][k] = bf16(W[k][m]) ---------------------
struct PackDesc { const float* src; unsigned short* dst; int K; int M; };
struct Pack7 { PackDesc d[7]; };
__global__ void pack_kernel(Pack7 p)
{
    PackDesc d = p.d[blockIdx.y];
    const int total = d.K * d.M;
    for (int idx = blockIdx.x * blockDim.x + threadIdx.x; idx < total;
         idx += gridDim.x * blockDim.x) {
        const int k = idx / d.M;
        const int m = idx - k * d.M;
        d.dst[(size_t)m * d.K + k] = f2bf(d.src[idx]);
    }
}

extern "C" void kernel_launch(void* const* d_in, const int* in_sizes, int n_in,
                              void* d_out, int out_size, void* d_ws, size_t ws_size,
                              hipStream_t stream)
{
    const float* x     = (const float*)d_in[0];
    const int*   ei    = (const int*)d_in[1];
    const float* enc_W = (const float*)d_in[2];
    const float* enc_b = (const float*)d_in[3];
    const float* bn_g  = (const float*)d_in[4];
    const float* bn_b  = (const float*)d_in[5];
    const float* gW1   = (const float*)d_in[6];
    const float* gb1   = (const float*)d_in[7];
    const float* gg    = (const float*)d_in[8];
    const float* gbb   = (const float*)d_in[9];
    const float* gW2   = (const float*)d_in[10];
    const float* gb2   = (const float*)d_in[11];
    const float* f2W1  = (const float*)d_in[12];
    const float* f2b1  = (const float*)d_in[13];
    const float* f2g1  = (const float*)d_in[14];
    const float* f2bb1 = (const float*)d_in[15];
    const float* f2W2  = (const float*)d_in[16];
    const float* f2b2  = (const float*)d_in[17];
    const float* f2g2  = (const float*)d_in[18];
    const float* f2bb2 = (const float*)d_in[19];
    const float* fnW1  = (const float*)d_in[20];
    const float* fnb1  = (const float*)d_in[21];
    const float* fng1  = (const float*)d_in[22];
    const float* fnbb1 = (const float*)d_in[23];
    const float* fnW2  = (const float*)d_in[24];
    const float* fnb2  = (const float*)d_in[25];
    const float* fng2  = (const float*)d_in[26];
    const float* fnbb2 = (const float*)d_in[27];

    const int D = 128;
    const int N = in_sizes[0] / D;   // 50000
    const int E = in_sizes[1] / 2;   // 640000
    const float invN = 1.0f / (float)N;

    // ---- workspace layout (all 256B-aligned chunks) ----
    char* w = (char*)d_ws;
    float* s0 = (float*)w;          // slot = [sum(width) | sumsq(width)]
    float* s1 = s0 + 256;           // width 128
    float* s3 = s1 + 256;           // width 256
    float* s4 = s3 + 512;           // width 128
    float* s5 = s4 + 256;           // width 512
    float* s6 = s5 + 1024;          // width 128
    float* sD = s6 + 256;           // dummy (GIN second linear has no BN)
    const size_t statsBytes = 2816 * sizeof(float);   // 11264
    size_t off = statsBytes;

    unsigned short* wpE  = (unsigned short*)(w + off); off += (size_t)128 * 128 * 2;
    unsigned short* wpG1 = (unsigned short*)(w + off); off += (size_t)128 * 128 * 2;
    unsigned short* wpG2 = (unsigned short*)(w + off); off += (size_t)128 * 128 * 2;
    unsigned short* wpF1 = (unsigned short*)(w + off); off += (size_t)128 * 256 * 2;
    unsigned short* wpF2 = (unsigned short*)(w + off); off += (size_t)256 * 128 * 2;
    unsigned short* wpN1 = (unsigned short*)(w + off); off += (size_t)128 * 512 * 2;
    unsigned short* wpN2 = (unsigned short*)(w + off); off += (size_t)512 * 128 * 2;

    unsigned short* P1 = (unsigned short*)(w + off); off += (size_t)N * 128 * 2; // t0,t1,t4,t6
    unsigned short* P2 = (unsigned short*)(w + off); off += (size_t)N * 128 * 2; // H,u,h3
    unsigned short* P3 = (unsigned short*)(w + off); off += (size_t)N * 128 * 2; // t2
    float*          Z  = (float*)(w + off);                                      // h+agg (fp32)
    unsigned short* T3 = (unsigned short*)(w + off); off += (size_t)N * 256 * 2; // t3/u3 (reuses Z)
    unsigned short* T5 = (unsigned short*)(w + off); off += (size_t)N * 512 * 2; // t5/u5

    hipMemsetAsync(d_ws, 0, statsBytes, stream);

    Pack7 pk;
    pk.d[0] = PackDesc{enc_W, wpE, 128, 128};
    pk.d[1] = PackDesc{gW1, wpG1, 128, 128};
    pk.d[2] = PackDesc{gW2, wpG2, 128, 128};
    pk.d[3] = PackDesc{f2W1, wpF1, 128, 256};
    pk.d[4] = PackDesc{f2W2, wpF2, 256, 128};
    pk.d[5] = PackDesc{fnW1, wpN1, 128, 512};
    pk.d[6] = PackDesc{fnW2, wpN2, 512, 128};
    pack_kernel<<<dim3(64, 7), 256, 0, stream>>>(pk);

    const int rb  = (N + 63) / 64;
    const int t4a = N * 128 / 4;
    const int t4b = N * 256 / 4;
    const int t4c = N * 512 / 4;
    const int ewb_a = (t4a + 255) / 256;
    const int ewb_b = (t4b + 255) / 256;
    const int ewb_c = (t4c + 255) / 256;

    // 1) t0 = x @ encW + enc_b            -> P1, stats s0
    gemm_kernel<128, true><<<dim3(rb, 2), 256, 0, stream>>>(x, wpE, enc_b, s0, s0 + 128, P1, N, 128);
    // 2) h = bn(t0): H (bf16) and Z (fp32, scatter target init)
    ew_kernel<<<ewb_a, 256, 0, stream>>>(P1, s0, s0 + 128, bn_g, bn_b, invN, 0,
                                         nullptr, nullptr, P2, Z, t4a, 127);
    // 3) Z[dst] += H[src]   (GIN aggregation)
    {
        long long th = (long long)E * 32;
        scatter_kernel<<<(int)((th + 255) / 256), 256, 0, stream>>>(ei, P2, Z, E);
    }
    // 4) t1 = Z @ gW1 + gb1               -> P1, stats s1
    gemm_kernel<128, true><<<dim3(rb, 2), 256, 0, stream>>>(Z, wpG1, gb1, s1, s1 + 128, P1, N, 128);
    // 5) u = gelu(bn(t1))                 -> P2
    ew_kernel<<<ewb_a, 256, 0, stream>>>(P1, s1, s1 + 128, gg, gbb, invN, 1,
                                         nullptr, nullptr, P2, nullptr, t4a, 127);
    // 6) t2 = u @ gW2 + gb2               -> P3 (no BN; dummy stats)
    gemm_kernel<128, false><<<dim3(rb, 2), 256, 0, stream>>>(P2, wpG2, gb2, sD, sD + 128, P3, N, 128);
    // 7) t3 = t2 @ f2W1 + f2b1            -> T3 [N,256], stats s3
    gemm_kernel<128, false><<<dim3(rb, 4), 256, 0, stream>>>(P3, wpF1, f2b1, s3, s3 + 256, T3, N, 256);
    // 8) u3 = gelu(bn(t3)) in-place
    ew_kernel<<<ewb_b, 256, 0, stream>>>(T3, s3, s3 + 256, f2g1, f2bb1, invN, 1,
                                         nullptr, nullptr, T3, nullptr, t4b, 255);
    // 9) t4 = u3 @ f2W2 + f2b2            -> P1, stats s4
    gemm_kernel<256, false><<<dim3(rb, 2), 256, 0, stream>>>(T3, wpF2, f2b2, s4, s4 + 128, P1, N, 128);
    // 10) h3 = bn(t4) + t2 + x            -> P2
    ew_kernel<<<ewb_a, 256, 0, stream>>>(P1, s4, s4 + 128, f2g2, f2bb2, invN, 0,
                                         P3, x, P2, nullptr, t4a, 127);
    // 11) t5 = h3 @ fnW1 + fnb1           -> T5 [N,512], stats s5
    gemm_kernel<128, false><<<dim3(rb, 8), 256, 0, stream>>>(P2, wpN1, fnb1, s5, s5 + 512, T5, N, 512);
    // 12) u5 = gelu(bn(t5)) in-place
    ew_kernel<<<ewb_c, 256, 0, stream>>>(T5, s5, s5 + 512, fng1, fnbb1, invN, 1,
                                         nullptr, nullptr, T5, nullptr, t4c, 511);
    // 13) t6 = u5 @ fnW2 + fnb2           -> P1, stats s6
    gemm_kernel<512, false><<<dim3(rb, 2), 256, 0, stream>>>(T5, wpN2, fnb2, s6, s6 + 128, P1, N, 128);
    // 14) out = bn(t6) + h3               -> d_out (fp32)
    ew_kernel<<<ewb_a, 256, 0, stream>>>(P1, s6, s6 + 128, fng2, fnbb2, invN, 0,
                                         P2, nullptr, nullptr, (float*)d_out, t4a, 127);

    (void)n_in; (void)out_size; (void)ws_size;
}

// Round 2
// 934.310 us; speedup vs baseline: 2.0334x; 2.0334x over previous
//
#include <hip/hip_runtime.h>
#include <hip/hip_bf16.h>

typedef __attribute__((ext_vector_type(8))) short short8;
typedef __attribute__((ext_vector_type(4))) float f32x4;

__device__ __forceinline__ float bf2f(unsigned short u) {
    union { unsigned int i; float f; } c;
    c.i = ((unsigned int)u) << 16;
    return c.f;
}
__device__ __forceinline__ unsigned short f2bf(float f) {
    union { float f; unsigned int i; } c;
    c.f = f;
    unsigned int x = c.i;
    x += 0x7FFFu + ((x >> 16) & 1u);
    return (unsigned short)(x >> 16);
}

// ---------------- GEMM: C[n,M] = A[n,K] @ W[K,M] + bias, bf16 MFMA ----------
// Wp is W pre-transposed to [M][K] bf16 (so B-fragments are contiguous).
// Also accumulates per-column sum / sumsq of (A@W+bias) over valid rows.
template<int K, bool AF32>
__global__ __launch_bounds__(256)
void gemm_kernel(const void* __restrict__ Av,
                 const unsigned short* __restrict__ Wp,
                 const float* __restrict__ bias,
                 float* __restrict__ ssum,
                 float* __restrict__ ssq,
                 unsigned short* __restrict__ C,
                 int nrows, int M)
{
    const int tid  = threadIdx.x;
    const int lane = tid & 63;
    const int wave = tid >> 6;
    const int wr = wave >> 1, wc = wave & 1;  // 2x2 waves, each 32x32
    const int lrow = lane & 15;
    const int kg   = lane >> 4;               // 0..3
    const int row0 = blockIdx.x * 64 + wr * 32;
    const int col0 = blockIdx.y * 64 + wc * 32;

    f32x4 acc00 = {0.f, 0.f, 0.f, 0.f};
    f32x4 acc01 = acc00, acc10 = acc00, acc11 = acc00;

    const int r0 = row0 + lrow;
    const int r1 = r0 + 16;
    const int r0c = r0 < nrows ? r0 : nrows - 1;   // clamp: loads stay in-bounds
    const int r1c = r1 < nrows ? r1 : nrows - 1;

    const unsigned short* w0p = Wp + (size_t)(col0 + lrow) * K + kg * 8;
    const unsigned short* w1p = w0p + (size_t)16 * K;

    #pragma unroll 4
    for (int k0 = 0; k0 < K; k0 += 32) {
        short8 a0, a1;
        if (AF32) {
            const float* A = (const float*)Av;
            const float* p0 = A + (size_t)r0c * K + k0 + kg * 8;
            const float* p1 = A + (size_t)r1c * K + k0 + kg * 8;
            f32x4 u0 = *(const f32x4*)p0;
            f32x4 u1 = *(const f32x4*)(p0 + 4);
            f32x4 v0 = *(const f32x4*)p1;
            f32x4 v1 = *(const f32x4*)(p1 + 4);
            #pragma unroll
            for (int j = 0; j < 4; ++j) {
                a0[j]     = (short)f2bf(u0[j]);
                a0[j + 4] = (short)f2bf(u1[j]);
                a1[j]     = (short)f2bf(v0[j]);
                a1[j + 4] = (short)f2bf(v1[j]);
            }
        } else {
            const unsigned short* A = (const unsigned short*)Av;
            a0 = *(const short8*)(A + (size_t)r0c * K + k0 + kg * 8);
            a1 = *(const short8*)(A + (size_t)r1c * K + k0 + kg * 8);
        }
        short8 b0 = *(const short8*)(w0p + k0);
        short8 b1 = *(const short8*)(w1p + k0);
        acc00 = __builtin_amdgcn_mfma_f32_16x16x32_bf16(a0, b0, acc00, 0, 0, 0);
        acc01 = __builtin_amdgcn_mfma_f32_16x16x32_bf16(a0, b1, acc01, 0, 0, 0);
        acc10 = __builtin_amdgcn_mfma_f32_16x16x32_bf16(a1, b0, acc10, 0, 0, 0);
        acc11 = __builtin_amdgcn_mfma_f32_16x16x32_bf16(a1, b1, acc11, 0, 0, 0);
    }

    // Epilogue: bias, bf16 store, per-column stats.
    // C/D layout (verified): col = lane&15, row = (lane>>4)*4 + i
    #pragma unroll
    for (int c = 0; c < 2; ++c) {
        const int col = col0 + c * 16 + lrow;
        const float bc = bias[col];
        float s = 0.f, q = 0.f;
        #pragma unroll
        for (int r = 0; r < 2; ++r) {
            f32x4 av;
            if (r == 0) av = c ? acc01 : acc00;
            else        av = c ? acc11 : acc10;
            const int rb = row0 + r * 16 + kg * 4;
            #pragma unroll
            for (int i = 0; i < 4; ++i) {
                const int row = rb + i;
                if (row < nrows) {
                    const float v = av[i] + bc;
                    C[(size_t)row * M + col] = f2bf(v);
                    s += v;
                    q += v * v;
                }
            }
        }
        s += __shfl_xor(s, 16); s += __shfl_xor(s, 32);
        q += __shfl_xor(q, 16); q += __shfl_xor(q, 32);
        if (kg == 0) {
            atomicAdd(&ssum[col], s);
            atomicAdd(&ssq[col], q);
        }
    }
}

// ---------------- elementwise: BN(+GELU)(+residuals), bf16/f32 outputs ------
__global__ void ew_kernel(const unsigned short* __restrict__ xin,
                          const float* __restrict__ ssum,
                          const float* __restrict__ ssq,
                          const float* __restrict__ gam,
                          const float* __restrict__ bet,
                          float invN, int do_gelu,
                          const unsigned short* __restrict__ res1,
                          const float* __restrict__ res2,
                          unsigned short* __restrict__ outb,
                          float* __restrict__ outf,
                          int total4, int cmask)
{
    int idx = blockIdx.x * blockDim.x + threadIdx.x;
    if (idx >= total4) return;
    const int base = idx * 4;
    const int c0 = base & cmask;

    ushort4 xv = *(const ushort4*)(xin + base);
    unsigned short xs[4] = {xv.x, xv.y, xv.z, xv.w};
    float r1[4] = {0.f, 0.f, 0.f, 0.f};
    float r2[4] = {0.f, 0.f, 0.f, 0.f};
    if (res1) {
        ushort4 rv = *(const ushort4*)(res1 + base);
        r1[0] = bf2f(rv.x); r1[1] = bf2f(rv.y); r1[2] = bf2f(rv.z); r1[3] = bf2f(rv.w);
    }
    if (res2) {
        float4 rv = *(const float4*)(res2 + base);
        r2[0] = rv.x; r2[1] = rv.y; r2[2] = rv.z; r2[3] = rv.w;
    }

    float o[4];
    #pragma unroll
    for (int j = 0; j < 4; ++j) {
        const int c = c0 + j;
        const float mean = ssum[c] * invN;
        const float var  = ssq[c] * invN - mean * mean;
        const float sc = gam[c] * rsqrtf(var + 1e-5f);
        const float sh = bet[c] - mean * sc;
        float v = sc * bf2f(xs[j]) + sh;
        if (do_gelu) v = 0.5f * v * (1.0f + erff(v * 0.70710678118f));
        o[j] = v + r1[j] + r2[j];
    }
    if (outb) {
        ushort4 ov;
        ov.x = f2bf(o[0]); ov.y = f2bf(o[1]); ov.z = f2bf(o[2]); ov.w = f2bf(o[3]);
        *(ushort4*)(outb + base) = ov;
    }
    if (outf) {
        float4 ov;
        ov.x = o[0]; ov.y = o[1]; ov.z = o[2]; ov.w = o[3];
        *(float4*)(outf + base) = ov;
    }
}

// ---------------- CSR build: histogram, 2-level scan, placement -------------
__global__ void hist_kernel(const int* __restrict__ ei, int* __restrict__ cnt, int E)
{
    int e = blockIdx.x * blockDim.x + threadIdx.x;
    if (e < E) atomicAdd(&cnt[ei[E + e]], 1);
}

__global__ void scan_reduce(const int* __restrict__ cnt, int* __restrict__ blksum, int n)
{
    __shared__ int s[256];
    int t = threadIdx.x;
    int i = blockIdx.x * 256 + t;
    s[t] = i < n ? cnt[i] : 0;
    __syncthreads();
    for (int d = 128; d > 0; d >>= 1) {
        if (t < d) s[t] += s[t + d];
        __syncthreads();
    }
    if (t == 0) blksum[blockIdx.x] = s[0];
}

__global__ void scan_top(int* __restrict__ blksum, int nb)
{
    __shared__ int s[256];
    int t = threadIdx.x;
    int v = t < nb ? blksum[t] : 0;
    s[t] = v;
    __syncthreads();
    for (int d = 1; d < 256; d <<= 1) {
        int u = (t >= d) ? s[t - d] : 0;
        __syncthreads();
        s[t] += u;
        __syncthreads();
    }
    if (t < nb) blksum[t] = s[t] - v;   // exclusive
}

__global__ void scan_apply(const int* __restrict__ cnt, const int* __restrict__ blksum,
                           int* __restrict__ offs, int* __restrict__ cursor, int n)
{
    __shared__ int s[256];
    int t = threadIdx.x;
    int i = blockIdx.x * 256 + t;
    int v = i < n ? cnt[i] : 0;
    s[t] = v;
    __syncthreads();
    for (int d = 1; d < 256; d <<= 1) {
        int u = (t >= d) ? s[t - d] : 0;
        __syncthreads();
        s[t] += u;
        __syncthreads();
    }
    int excl = s[t] - v + blksum[blockIdx.x];
    if (i < n) { offs[i] = excl; cursor[i] = excl; }
}

__global__ void place_kernel(const int* __restrict__ ei, int* __restrict__ cursor,
                             int* __restrict__ ssrc, int E)
{
    int e = blockIdx.x * blockDim.x + threadIdx.x;
    if (e < E) {
        int pos = atomicAdd(&cursor[ei[E + e]], 1);
        ssrc[pos] = ei[e];
    }
}

// ---------------- GIN gather: Z[i] = H[i] + sum_{j in nbr(i)} H[j] ----------
__global__ __launch_bounds__(256)
void gather_kernel(const unsigned short* __restrict__ H,
                   const int* __restrict__ ssrc,
                   const int* __restrict__ offs,
                   const int* __restrict__ cnt,
                   unsigned short* __restrict__ Zb, int N)
{
    const int wave = threadIdx.x >> 6;
    const int lane = threadIdx.x & 63;
    const int node = blockIdx.x * 4 + wave;
    if (node >= N) return;

    unsigned int hv = *(const unsigned int*)(H + (size_t)node * 128 + lane * 2);
    float a0 = bf2f((unsigned short)hv);
    float a1 = bf2f((unsigned short)(hv >> 16));

    const int off = offs[node];
    const int deg = cnt[node];
    for (int base = 0; base < deg; base += 64) {
        int m = deg - base;
        if (m > 64) m = 64;
        int idx = (base + lane < deg) ? ssrc[off + base + lane] : 0;
        int k = 0;
        for (; k + 1 < m; k += 2) {
            int s0 = __shfl(idx, k);
            int s1 = __shfl(idx, k + 1);
            unsigned int v0 = *(const unsigned int*)(H + (size_t)s0 * 128 + lane * 2);
            unsigned int v1 = *(const unsigned int*)(H + (size_t)s1 * 128 + lane * 2);
            a0 += bf2f((unsigned short)v0) + bf2f((unsigned short)v1);
            a1 += bf2f((unsigned short)(v0 >> 16)) + bf2f((unsigned short)(v1 >> 16));
        }
        if (k < m) {
            int s0 = __shfl(idx, k);
            unsigned int v0 = *(const unsigned int*)(H + (size_t)s0 * 128 + lane * 2);
            a0 += bf2f((unsigned short)v0);
            a1 += bf2f((unsigned short)(v0 >> 16));
        }
    }
    unsigned int o = ((unsigned int)f2bf(a1) << 16) | (unsigned int)f2bf(a0);
    *(unsigned int*)(Zb + (size_t)node * 128 + lane * 2) = o;
}

// ---------------- weight pack: Wp[m][k] = bf16(W[k][m]) ---------------------
struct PackDesc { const float* src; unsigned short* dst; int K; int M; };
struct Pack7 { PackDesc d[7]; };
__global__ void pack_kernel(Pack7 p)
{
    PackDesc d = p.d[blockIdx.y];
    const int total = d.K * d.M;
    for (int idx = blockIdx.x * blockDim.x + threadIdx.x; idx < total;
         idx += gridDim.x * blockDim.x) {
        const int k = idx / d.M;
        const int m = idx - k * d.M;
        d.dst[(size_t)m * d.K + k] = f2bf(d.src[idx]);
    }
}

extern "C" void kernel_launch(void* const* d_in, const int* in_sizes, int n_in,
                              void* d_out, int out_size, void* d_ws, size_t ws_size,
                              hipStream_t stream)
{
    const float* x     = (const float*)d_in[0];
    const int*   ei    = (const int*)d_in[1];
    const float* enc_W = (const float*)d_in[2];
    const float* enc_b = (const float*)d_in[3];
    const float* bn_g  = (const float*)d_in[4];
    const float* bn_b  = (const float*)d_in[5];
    const float* gW1   = (const float*)d_in[6];
    const float* gb1   = (const float*)d_in[7];
    const float* gg    = (const float*)d_in[8];
    const float* gbb   = (const float*)d_in[9];
    const float* gW2   = (const float*)d_in[10];
    const float* gb2   = (const float*)d_in[11];
    const float* f2W1  = (const float*)d_in[12];
    const float* f2b1  = (const float*)d_in[13];
    const float* f2g1  = (const float*)d_in[14];
    const float* f2bb1 = (const float*)d_in[15];
    const float* f2W2  = (const float*)d_in[16];
    const float* f2b2  = (const float*)d_in[17];
    const float* f2g2  = (const float*)d_in[18];
    const float* f2bb2 = (const float*)d_in[19];
    const float* fnW1  = (const float*)d_in[20];
    const float* fnb1  = (const float*)d_in[21];
    const float* fng1  = (const float*)d_in[22];
    const float* fnbb1 = (const float*)d_in[23];
    const float* fnW2  = (const float*)d_in[24];
    const float* fnb2  = (const float*)d_in[25];
    const float* fng2  = (const float*)d_in[26];
    const float* fnbb2 = (const float*)d_in[27];

    const int D = 128;
    const int N = in_sizes[0] / D;   // 50000
    const int E = in_sizes[1] / 2;   // 640000
    const float invN = 1.0f / (float)N;

    // ---- workspace layout ----
    char* w = (char*)d_ws;
    float* s0 = (float*)w;          // slot = [sum(width) | sumsq(width)]
    float* s1 = s0 + 256;           // width 128
    float* s3 = s1 + 256;           // width 256
    float* s4 = s3 + 512;           // width 128
    float* s5 = s4 + 256;           // width 512
    float* s6 = s5 + 1024;          // width 128
    float* sD = s6 + 256;           // dummy (GIN second linear has no BN)
    const size_t statsBytes = 2816 * sizeof(float);
    size_t off = statsBytes;

    unsigned short* wpE  = (unsigned short*)(w + off); off += (size_t)128 * 128 * 2;
    unsigned short* wpG1 = (unsigned short*)(w + off); off += (size_t)128 * 128 * 2;
    unsigned short* wpG2 = (unsigned short*)(w + off); off += (size_t)128 * 128 * 2;
    unsigned short* wpF1 = (unsigned short*)(w + off); off += (size_t)128 * 256 * 2;
    unsigned short* wpF2 = (unsigned short*)(w + off); off += (size_t)256 * 128 * 2;
    unsigned short* wpN1 = (unsigned short*)(w + off); off += (size_t)128 * 512 * 2;
    unsigned short* wpN2 = (unsigned short*)(w + off); off += (size_t)512 * 128 * 2;

    unsigned short* P1 = (unsigned short*)(w + off); off += (size_t)N * 128 * 2; // t0,t1,t4,t6
    unsigned short* P2 = (unsigned short*)(w + off); off += (size_t)N * 128 * 2; // H,u,h3
    unsigned short* P3 = (unsigned short*)(w + off); off += (size_t)N * 128 * 2; // t2
    unsigned short* Zb = (unsigned short*)(w + off);                             // h+agg (bf16)
    unsigned short* T3 = (unsigned short*)(w + off); off += (size_t)N * 256 * 2; // t3/u3 (reuses Zb slot)
    unsigned short* T5 = (unsigned short*)(w + off); off += (size_t)N * 512 * 2; // t5/u5

    // CSR arrays live inside the T5 region (lifetimes don't overlap:
    // CSR is dead after gather; T5 is first written at step 11).
    const int NB = (N + 255) / 256;              // scan blocks (must be <= 256)
    char* csr = (char*)T5;
    int* cnt    = (int*)csr;                       csr += (size_t)NB * 256 * 4;
    int* offs   = (int*)csr;                       csr += (size_t)NB * 256 * 4;
    int* cursor = (int*)csr;                       csr += (size_t)NB * 256 * 4;
    int* blksum = (int*)csr;                       csr += 1024;
    int* ssrc   = (int*)csr;

    hipMemsetAsync(d_ws, 0, statsBytes, stream);
    hipMemsetAsync(cnt, 0, (size_t)NB * 256 * 4, stream);

    Pack7 pk;
    pk.d[0] = PackDesc{enc_W, wpE, 128, 128};
    pk.d[1] = PackDesc{gW1, wpG1, 128, 128};
    pk.d[2] = PackDesc{gW2, wpG2, 128, 128};
    pk.d[3] = PackDesc{f2W1, wpF1, 128, 256};
    pk.d[4] = PackDesc{f2W2, wpF2, 256, 128};
    pk.d[5] = PackDesc{fnW1, wpN1, 128, 512};
    pk.d[6] = PackDesc{fnW2, wpN2, 512, 128};
    pack_kernel<<<dim3(64, 7), 256, 0, stream>>>(pk);

    const int rb  = (N + 63) / 64;
    const int eb  = (E + 255) / 256;
    const int t4a = N * 128 / 4;
    const int t4b = N * 256 / 4;
    const int t4c = N * 512 / 4;
    const int ewb_a = (t4a + 255) / 256;
    const int ewb_b = (t4b + 255) / 256;
    const int ewb_c = (t4c + 255) / 256;

    // ---- CSR build (overlaps with encoder GEMM dependency-wise, same stream)
    hist_kernel<<<eb, 256, 0, stream>>>(ei, cnt, E);
    scan_reduce<<<NB, 256, 0, stream>>>(cnt, blksum, N);
    scan_top<<<1, 256, 0, stream>>>(blksum, NB);
    scan_apply<<<NB, 256, 0, stream>>>(cnt, blksum, offs, cursor, N);
    place_kernel<<<eb, 256, 0, stream>>>(ei, cursor, ssrc, E);

    // 1) t0 = x @ encW + enc_b            -> P1, stats s0
    gemm_kernel<128, true><<<dim3(rb, 2), 256, 0, stream>>>(x, wpE, enc_b, s0, s0 + 128, P1, N, 128);
    // 2) h = bn(t0)                       -> P2 (bf16)
    ew_kernel<<<ewb_a, 256, 0, stream>>>(P1, s0, s0 + 128, bn_g, bn_b, invN, 0,
                                         nullptr, nullptr, P2, nullptr, t4a, 127);
    // 3) Z = h + sum_{nbr} h              -> Zb (bf16)
    gather_kernel<<<(N + 3) / 4, 256, 0, stream>>>(P2, ssrc, offs, cnt, Zb, N);
    // 4) t1 = Z @ gW1 + gb1               -> P1, stats s1
    gemm_kernel<128, false><<<dim3(rb, 2), 256, 0, stream>>>(Zb, wpG1, gb1, s1, s1 + 128, P1, N, 128);
    // 5) u = gelu(bn(t1))                 -> P2
    ew_kernel<<<ewb_a, 256, 0, stream>>>(P1, s1, s1 + 128, gg, gbb, invN, 1,
                                         nullptr, nullptr, P2, nullptr, t4a, 127);
    // 6) t2 = u @ gW2 + gb2               -> P3 (no BN; dummy stats)
    gemm_kernel<128, false><<<dim3(rb, 2), 256, 0, stream>>>(P2, wpG2, gb2, sD, sD + 128, P3, N, 128);
    // 7) t3 = t2 @ f2W1 + f2b1            -> T3 [N,256], stats s3
    gemm_kernel<128, false><<<dim3(rb, 4), 256, 0, stream>>>(P3, wpF1, f2b1, s3, s3 + 256, T3, N, 256);
    // 8) u3 = gelu(bn(t3)) in-place
    ew_kernel<<<ewb_b, 256, 0, stream>>>(T3, s3, s3 + 256, f2g1, f2bb1, invN, 1,
                                         nullptr, nullptr, T3, nullptr, t4b, 255);
    // 9) t4 = u3 @ f2W2 + f2b2            -> P1, stats s4
    gemm_kernel<256, false><<<dim3(rb, 2), 256, 0, stream>>>(T3, wpF2, f2b2, s4, s4 + 128, P1, N, 128);
    // 10) h3 = bn(t4) + t2 + x            -> P2
    ew_kernel<<<ewb_a, 256, 0, stream>>>(P1, s4, s4 + 128, f2g2, f2bb2, invN, 0,
                                         P3, x, P2, nullptr, t4a, 127);
    // 11) t5 = h3 @ fnW1 + fnb1           -> T5 [N,512], stats s5
    gemm_kernel<128, false><<<dim3(rb, 8), 256, 0, stream>>>(P2, wpN1, fnb1, s5, s5 + 512, T5, N, 512);
    // 12) u5 = gelu(bn(t5)) in-place
    ew_kernel<<<ewb_c, 256, 0, stream>>>(T5, s5, s5 + 512, fng1, fnbb1, invN, 1,
                                         nullptr, nullptr, T5, nullptr, t4c, 511);
    // 13) t6 = u5 @ fnW2 + fnb2           -> P1, stats s6
    gemm_kernel<512, false><<<dim3(rb, 2), 256, 0, stream>>>(T5, wpN2, fnb2, s6, s6 + 128, P1, N, 128);
    // 14) out = bn(t6) + h3               -> d_out (fp32)
    ew_kernel<<<ewb_a, 256, 0, stream>>>(P1, s6, s6 + 128, fng2, fnbb2, invN, 0,
                                         P2, nullptr, nullptr, (float*)d_out, t4a, 127);

    (void)n_in; (void)out_size; (void)ws_size;
}

// Round 3
// 574.303 us; speedup vs baseline: 3.3081x; 1.6269x over previous
//
#include <hip/hip_runtime.h>
#include <hip/hip_bf16.h>

typedef __attribute__((ext_vector_type(8))) short short8;
typedef __attribute__((ext_vector_type(4))) float f32x4;

__device__ __forceinline__ float bf2f(unsigned short u) {
    union { unsigned int i; float f; } c;
    c.i = ((unsigned int)u) << 16;
    return c.f;
}
__device__ __forceinline__ unsigned short f2bf(float f) {
    union { float f; unsigned int i; } c;
    c.f = f;
    unsigned int x = c.i;
    x += 0x7FFFu + ((x >> 16) & 1u);
    return (unsigned short)(x >> 16);
}

// ---------------- fused GEMM: C[n,M] = f(A)[n,K] @ W[K,M] + bias ------------
// One block = 64-row stripe x FULL M. B (Wp, [M][K] bf16) staged to LDS in
// MFMA-fragment-contiguous layout (frag = 1KB = 64 lanes x 16B, lane = kg*16+lrow).
// A staged global->reg->transform->LDS in the same layout. Single barrier, then
// pure LDS+MFMA K-loop. XF: 0=none, 1=fp32 cast, 2=BN+GELU, 3=BN+res1(bf16)+res2(f32)
// (XF3 also side-writes the transformed A row-stripe to h3out, once per element).
template<int K, int M, int XF>
__global__ __launch_bounds__((M == 512) ? 512 : 256)
void gemmf_kernel(const void* __restrict__ Av,
                  const float* __restrict__ pSum, const float* __restrict__ pSq,
                  const float* __restrict__ pG, const float* __restrict__ pB,
                  const unsigned short* __restrict__ res1,
                  const float* __restrict__ res2,
                  unsigned short* __restrict__ h3out,
                  const unsigned short* __restrict__ Wp,
                  const float* __restrict__ bias,
                  float* __restrict__ ssum, float* __restrict__ ssq,
                  unsigned short* __restrict__ C,
                  int nrows, float invN)
{
    constexpr int NW  = (M == 512) ? 8 : 4;        // waves
    constexpr int KC  = (K > 256) ? 256 : K;       // K-chunk held in LDS
    constexpr int NKC = K / KC;
    constexpr int KS  = KC / 32;                   // k-steps per chunk
    constexpr int NR  = 4;                         // row-blocks (64 rows)
    constexpr int NCW = M / (NW * 16);             // col-blocks per wave
    constexpr int NFA = NR * KS;                   // A fragments per chunk
    constexpr int NFB = (M / 16) * KS;             // B fragments per chunk
    __shared__ __align__(16) char smem[(NFA + NFB) * 1024];

    const int tid = threadIdx.x;
    const int l   = tid & 63, wv = tid >> 6;
    const int gr0 = blockIdx.x * 64;

    f32x4 acc[NR][NCW];
    #pragma unroll
    for (int r = 0; r < NR; ++r)
        #pragma unroll
        for (int c = 0; c < NCW; ++c) acc[r][c] = f32x4{0.f, 0.f, 0.f, 0.f};

    // staging lane mapping: consecutive 4 lanes -> consecutive k8 (64B global runs)
    const int kq4 = l & 3, rloc = l >> 2;

    for (int kc = 0; kc < NKC; ++kc) {
        const int kcb = kc * KC;
        // ---- stage A (transform fused) ----
        #pragma unroll
        for (int i = 0; i < NFA / NW; ++i) {
            const int f = i * NW + wv;
            const int rowblk = f / KS, kstep = f % KS;
            const int row = rowblk * 16 + rloc;
            int rowg = gr0 + row;
            const bool valid = rowg < nrows;
            if (!valid) rowg = nrows - 1;
            const int k8 = kstep * 4 + kq4;
            const int c0 = kcb + k8 * 8;
            const size_t eoff = (size_t)rowg * K + c0;
            short8 val;
            if (XF == 0) {
                val = *(const short8*)((const unsigned short*)Av + eoff);
            } else if (XF == 1) {
                const float* A = (const float*)Av;
                f32x4 u0 = *(const f32x4*)(A + eoff);
                f32x4 u1 = *(const f32x4*)(A + eoff + 4);
                #pragma unroll
                for (int j = 0; j < 4; ++j) {
                    val[j]     = (short)f2bf(u0[j]);
                    val[j + 4] = (short)f2bf(u1[j]);
                }
            } else {
                short8 t = *(const short8*)((const unsigned short*)Av + eoff);
                float o[8];
                #pragma unroll
                for (int j = 0; j < 8; ++j) {
                    const int c = c0 + j;
                    const float mean = pSum[c] * invN;
                    const float var  = pSq[c] * invN - mean * mean;
                    const float sc   = pG[c] * rsqrtf(var + 1e-5f);
                    const float sh   = pB[c] - mean * sc;
                    float v = sc * bf2f((unsigned short)t[j]) + sh;
                    if (XF == 2) v = 0.5f * v * (1.0f + erff(v * 0.70710678118f));
                    o[j] = v;
                }
                if (XF == 3) {
                    short8 r1 = *(const short8*)(res1 + eoff);
                    f32x4 x0 = *(const f32x4*)(res2 + eoff);
                    f32x4 x1 = *(const f32x4*)(res2 + eoff + 4);
                    #pragma unroll
                    for (int j = 0; j < 4; ++j) {
                        o[j]     += bf2f((unsigned short)r1[j])     + x0[j];
                        o[j + 4] += bf2f((unsigned short)r1[j + 4]) + x1[j];
                    }
                }
                #pragma unroll
                for (int j = 0; j < 8; ++j) val[j] = (short)f2bf(o[j]);
                if (XF == 3 && valid) *(short8*)(h3out + eoff) = val;
            }
            *(short8*)(smem + f * 1024 + (kq4 * 16 + rloc) * 16) = val;
        }
        // ---- stage B ----
        #pragma unroll
        for (int i = 0; i < NFB / NW; ++i) {
            const int f = i * NW + wv;
            const int colblk = f / KS, kstep = f % KS;
            const int col = colblk * 16 + rloc;
            const int k8 = kstep * 4 + kq4;
            const size_t eoff = (size_t)col * K + kcb + k8 * 8;
            *(short8*)(smem + (NFA + f) * 1024 + (kq4 * 16 + rloc) * 16) =
                *(const short8*)(Wp + eoff);
        }
        __syncthreads();
        // ---- MFMA K-loop, all operands LDS-resident ----
        #pragma unroll
        for (int ks = 0; ks < KS; ++ks) {
            short8 af[NR], bfr[NCW];
            #pragma unroll
            for (int r = 0; r < NR; ++r)
                af[r] = *(const short8*)(smem + (r * KS + ks) * 1024 + l * 16);
            #pragma unroll
            for (int c = 0; c < NCW; ++c)
                bfr[c] = *(const short8*)(smem + (NFA + (wv * NCW + c) * KS + ks) * 1024 + l * 16);
            #pragma unroll
            for (int r = 0; r < NR; ++r)
                #pragma unroll
                for (int c = 0; c < NCW; ++c)
                    acc[r][c] = __builtin_amdgcn_mfma_f32_16x16x32_bf16(af[r], bfr[c], acc[r][c], 0, 0, 0);
        }
        if (kc + 1 < NKC) __syncthreads();
    }

    // ---- epilogue: bias, bf16 store, per-column stats ----
    const int lrow = l & 15, kg = l >> 4;
    #pragma unroll
    for (int c = 0; c < NCW; ++c) {
        const int col = (wv * NCW + c) * 16 + lrow;
        const float bc = bias[col];
        float s = 0.f, q = 0.f;
        #pragma unroll
        for (int r = 0; r < NR; ++r) {
            const int rb = gr0 + r * 16 + kg * 4;
            #pragma unroll
            for (int i = 0; i < 4; ++i) {
                const int row = rb + i;
                if (row < nrows) {
                    const float v = acc[r][c][i] + bc;
                    C[(size_t)row * M + col] = f2bf(v);
                    s += v; q += v * v;
                }
            }
        }
        s += __shfl_xor(s, 16); s += __shfl_xor(s, 32);
        q += __shfl_xor(q, 16); q += __shfl_xor(q, 32);
        if (kg == 0 && ssum != nullptr) {
            atomicAdd(&ssum[col], s);
            atomicAdd(&ssq[col], q);
        }
    }
}

// ---------------- CSR build ------------------------------------------------
__global__ void hist_kernel(const int* __restrict__ ei, int* __restrict__ cnt, int E)
{
    int e = blockIdx.x * blockDim.x + threadIdx.x;
    if (e < E) atomicAdd(&cnt[ei[E + e]], 1);
}

__global__ void scan_reduce(const int* __restrict__ cnt, int* __restrict__ blksum, int n)
{
    __shared__ int s[256];
    int t = threadIdx.x;
    int i = blockIdx.x * 256 + t;
    s[t] = i < n ? cnt[i] : 0;
    __syncthreads();
    for (int d = 128; d > 0; d >>= 1) {
        if (t < d) s[t] += s[t + d];
        __syncthreads();
    }
    if (t == 0) blksum[blockIdx.x] = s[0];
}

__global__ void scan_top(int* __restrict__ blksum, int nb)
{
    __shared__ int s[256];
    int t = threadIdx.x;
    int v = t < nb ? blksum[t] : 0;
    s[t] = v;
    __syncthreads();
    for (int d = 1; d < 256; d <<= 1) {
        int u = (t >= d) ? s[t - d] : 0;
        __syncthreads();
        s[t] += u;
        __syncthreads();
    }
    if (t < nb) blksum[t] = s[t] - v;   // exclusive
}

__global__ void scan_apply(const int* __restrict__ cnt, const int* __restrict__ blksum,
                           int* __restrict__ offs, int* __restrict__ cursor, int n)
{
    __shared__ int s[256];
    int t = threadIdx.x;
    int i = blockIdx.x * 256 + t;
    int v = i < n ? cnt[i] : 0;
    s[t] = v;
    __syncthreads();
    for (int d = 1; d < 256; d <<= 1) {
        int u = (t >= d) ? s[t - d] : 0;
        __syncthreads();
        s[t] += u;
        __syncthreads();
    }
    int excl = s[t] - v + blksum[blockIdx.x];
    if (i < n) { offs[i] = excl; cursor[i] = excl; }
}

__global__ void place_kernel(const int* __restrict__ ei, int* __restrict__ cursor,
                             int* __restrict__ ssrc, int E)
{
    int e = blockIdx.x * blockDim.x + threadIdx.x;
    if (e < E) {
        int pos = atomicAdd(&cursor[ei[E + e]], 1);
        ssrc[pos] = ei[e];
    }
}

// ---------------- GIN gather with fused BN0 --------------------------------
// Z_i = sc o (t0_i + sum_j t0_j) + (deg_i + 1) * sh   (affine commutes w/ sum)
__global__ __launch_bounds__(256)
void gather_kernel(const unsigned short* __restrict__ T0,
                   const float* __restrict__ pSum, const float* __restrict__ pSq,
                   const float* __restrict__ pG, const float* __restrict__ pB,
                   float invN,
                   const int* __restrict__ ssrc, const int* __restrict__ offs,
                   const int* __restrict__ cnt,
                   unsigned short* __restrict__ Zb, int N)
{
    const int wave = threadIdx.x >> 6;
    const int lane = threadIdx.x & 63;
    const int node = blockIdx.x * 4 + wave;
    if (node >= N) return;

    unsigned int hv = *(const unsigned int*)(T0 + (size_t)node * 128 + lane * 2);
    float a0 = bf2f((unsigned short)hv);
    float a1 = bf2f((unsigned short)(hv >> 16));

    const int off = offs[node];
    const int deg = cnt[node];
    for (int base = 0; base < deg; base += 64) {
        int m = deg - base;
        if (m > 64) m = 64;
        int idx = (base + lane < deg) ? ssrc[off + base + lane] : 0;
        int k = 0;
        for (; k + 1 < m; k += 2) {
            int s0 = __shfl(idx, k);
            int s1 = __shfl(idx, k + 1);
            unsigned int v0 = *(const unsigned int*)(T0 + (size_t)s0 * 128 + lane * 2);
            unsigned int v1 = *(const unsigned int*)(T0 + (size_t)s1 * 128 + lane * 2);
            a0 += bf2f((unsigned short)v0) + bf2f((unsigned short)v1);
            a1 += bf2f((unsigned short)(v0 >> 16)) + bf2f((unsigned short)(v1 >> 16));
        }
        if (k < m) {
            int s0 = __shfl(idx, k);
            unsigned int v0 = *(const unsigned int*)(T0 + (size_t)s0 * 128 + lane * 2);
            a0 += bf2f((unsigned short)v0);
            a1 += bf2f((unsigned short)(v0 >> 16));
        }
    }
    const int c0 = lane * 2;
    const float mean0 = pSum[c0] * invN;
    const float var0  = pSq[c0] * invN - mean0 * mean0;
    const float sc0   = pG[c0] * rsqrtf(var0 + 1e-5f);
    const float sh0   = pB[c0] - mean0 * sc0;
    const float mean1 = pSum[c0 + 1] * invN;
    const float var1  = pSq[c0 + 1] * invN - mean1 * mean1;
    const float sc1   = pG[c0 + 1] * rsqrtf(var1 + 1e-5f);
    const float sh1   = pB[c0 + 1] - mean1 * sc1;
    const float dp1 = (float)(deg + 1);
    const float z0 = sc0 * a0 + dp1 * sh0;
    const float z1 = sc1 * a1 + dp1 * sh1;
    unsigned int o = ((unsigned int)f2bf(z1) << 16) | (unsigned int)f2bf(z0);
    *(unsigned int*)(Zb + (size_t)node * 128 + lane * 2) = o;
}

// ---------------- final: out = bn(t6) + h3 (fp32) --------------------------
__global__ void final_kernel(const unsigned short* __restrict__ t6,
                             const float* __restrict__ pSum, const float* __restrict__ pSq,
                             const float* __restrict__ pG, const float* __restrict__ pB,
                             const unsigned short* __restrict__ h3,
                             float* __restrict__ out, float invN, int total4)
{
    int idx = blockIdx.x * blockDim.x + threadIdx.x;
    if (idx >= total4) return;
    const int base = idx * 4;
    const int c0 = base & 127;
    ushort4 tv = *(const ushort4*)(t6 + base);
    ushort4 hv = *(const ushort4*)(h3 + base);
    unsigned short ts[4] = {tv.x, tv.y, tv.z, tv.w};
    unsigned short hs[4] = {hv.x, hv.y, hv.z, hv.w};
    float4 ov;
    float* po = &ov.x;
    #pragma unroll
    for (int j = 0; j < 4; ++j) {
        const int c = c0 + j;
        const float mean = pSum[c] * invN;
        const float var  = pSq[c] * invN - mean * mean;
        const float sc   = pG[c] * rsqrtf(var + 1e-5f);
        const float sh   = pB[c] - mean * sc;
        po[j] = sc * bf2f(ts[j]) + sh + bf2f(hs[j]);
    }
    *(float4*)(out + base) = ov;
}

// ---------------- weight pack: Wp[m][k] = bf16(W[k][m]) ---------------------
struct PackDesc { const float* src; unsigned short* dst; int K; int M; };
struct Pack7 { PackDesc d[7]; };
__global__ void pack_kernel(Pack7 p)
{
    PackDesc d = p.d[blockIdx.y];
    const int total = d.K * d.M;
    for (int idx = blockIdx.x * blockDim.x + threadIdx.x; idx < total;
         idx += gridDim.x * blockDim.x) {
        const int k = idx / d.M;
        const int m = idx - k * d.M;
        d.dst[(size_t)m * d.K + k] = f2bf(d.src[idx]);
    }
}

extern "C" void kernel_launch(void* const* d_in, const int* in_sizes, int n_in,
                              void* d_out, int out_size, void* d_ws, size_t ws_size,
                              hipStream_t stream)
{
    const float* x     = (const float*)d_in[0];
    const int*   ei    = (const int*)d_in[1];
    const float* enc_W = (const float*)d_in[2];
    const float* enc_b = (const float*)d_in[3];
    const float* bn_g  = (const float*)d_in[4];
    const float* bn_b  = (const float*)d_in[5];
    const float* gW1   = (const float*)d_in[6];
    const float* gb1   = (const float*)d_in[7];
    const float* gg    = (const float*)d_in[8];
    const float* gbb   = (const float*)d_in[9];
    const float* gW2   = (const float*)d_in[10];
    const float* gb2   = (const float*)d_in[11];
    const float* f2W1  = (const float*)d_in[12];
    const float* f2b1  = (const float*)d_in[13];
    const float* f2g1  = (const float*)d_in[14];
    const float* f2bb1 = (const float*)d_in[15];
    const float* f2W2  = (const float*)d_in[16];
    const float* f2b2  = (const float*)d_in[17];
    const float* f2g2  = (const float*)d_in[18];
    const float* f2bb2 = (const float*)d_in[19];
    const float* fnW1  = (const float*)d_in[20];
    const float* fnb1  = (const float*)d_in[21];
    const float* fng1  = (const float*)d_in[22];
    const float* fnbb1 = (const float*)d_in[23];
    const float* fnW2  = (const float*)d_in[24];
    const float* fnb2  = (const float*)d_in[25];
    const float* fng2  = (const float*)d_in[26];
    const float* fnbb2 = (const float*)d_in[27];

    const int D = 128;
    const int N = in_sizes[0] / D;   // 50000
    const int E = in_sizes[1] / 2;   // 640000
    const float invN = 1.0f / (float)N;

    // ---- workspace layout ----
    char* w = (char*)d_ws;
    float* s0 = (float*)w;          // [sum(128) | sq(128)]
    float* s1 = s0 + 256;           // [sum(128) | sq(128)]
    float* s3 = s1 + 256;           // [sum(256) | sq(256)]
    float* s4 = s3 + 512;           // [sum(128) | sq(128)]
    float* s5 = s4 + 256;           // [sum(512) | sq(512)]
    float* s6 = s5 + 1024;          // [sum(128) | sq(128)]
    const size_t statsBytes = 2560 * sizeof(float);
    size_t off = statsBytes;

    unsigned short* wpE  = (unsigned short*)(w + off); off += (size_t)128 * 128 * 2;
    unsigned short* wpG1 = (unsigned short*)(w + off); off += (size_t)128 * 128 * 2;
    unsigned short* wpG2 = (unsigned short*)(w + off); off += (size_t)128 * 128 * 2;
    unsigned short* wpF1 = (unsigned short*)(w + off); off += (size_t)128 * 256 * 2;
    unsigned short* wpF2 = (unsigned short*)(w + off); off += (size_t)256 * 128 * 2;
    unsigned short* wpN1 = (unsigned short*)(w + off); off += (size_t)128 * 512 * 2;
    unsigned short* wpN2 = (unsigned short*)(w + off); off += (size_t)512 * 128 * 2;

    unsigned short* P1 = (unsigned short*)(w + off); off += (size_t)N * 128 * 2; // t0,t1,t4,t6
    unsigned short* Zb = (unsigned short*)(w + off); off += (size_t)N * 128 * 2; // Z, t2
    unsigned short* H3 = (unsigned short*)(w + off); off += (size_t)N * 128 * 2; // h3
    unsigned short* T3 = (unsigned short*)(w + off); off += (size_t)N * 256 * 2; // t3
    unsigned short* T5 = (unsigned short*)(w + off); off += (size_t)N * 512 * 2; // t5

    // CSR arrays inside T5 (CSR dead after gather; T5 first written at GEMM-6)
    const int NB = (N + 255) / 256;
    char* csr = (char*)T5;
    int* cnt    = (int*)csr;  csr += (size_t)NB * 256 * 4;
    int* offs   = (int*)csr;  csr += (size_t)NB * 256 * 4;
    int* cursor = (int*)csr;  csr += (size_t)NB * 256 * 4;
    int* blksum = (int*)csr;  csr += 1024;
    int* ssrc   = (int*)csr;

    hipMemsetAsync(d_ws, 0, statsBytes, stream);
    hipMemsetAsync(cnt, 0, (size_t)NB * 256 * 4, stream);

    Pack7 pk;
    pk.d[0] = PackDesc{enc_W, wpE, 128, 128};
    pk.d[1] = PackDesc{gW1, wpG1, 128, 128};
    pk.d[2] = PackDesc{gW2, wpG2, 128, 128};
    pk.d[3] = PackDesc{f2W1, wpF1, 128, 256};
    pk.d[4] = PackDesc{f2W2, wpF2, 256, 128};
    pk.d[5] = PackDesc{fnW1, wpN1, 128, 512};
    pk.d[6] = PackDesc{fnW2, wpN2, 512, 128};
    pack_kernel<<<dim3(64, 7), 256, 0, stream>>>(pk);

    const int eb = (E + 255) / 256;
    hist_kernel<<<eb, 256, 0, stream>>>(ei, cnt, E);
    scan_reduce<<<NB, 256, 0, stream>>>(cnt, blksum, N);
    scan_top<<<1, 256, 0, stream>>>(blksum, NB);
    scan_apply<<<NB, 256, 0, stream>>>(cnt, blksum, offs, cursor, N);
    place_kernel<<<eb, 256, 0, stream>>>(ei, cursor, ssrc, E);

    const int rb  = (N + 63) / 64;
    const int t4a = N * 128 / 4;

    // 1) t0 = x @ encW + enc_b                       -> P1, stats s0
    gemmf_kernel<128, 128, 1><<<rb, 256, 0, stream>>>(
        x, nullptr, nullptr, nullptr, nullptr, nullptr, nullptr, nullptr,
        wpE, enc_b, s0, s0 + 128, P1, N, invN);
    // 2) Z = bn0(t0 self+agg)                        -> Zb
    gather_kernel<<<(N + 3) / 4, 256, 0, stream>>>(
        P1, s0, s0 + 128, bn_g, bn_b, invN, ssrc, offs, cnt, Zb, N);
    // 3) t1 = Z @ gW1 + gb1                          -> P1, stats s1
    gemmf_kernel<128, 128, 0><<<rb, 256, 0, stream>>>(
        Zb, nullptr, nullptr, nullptr, nullptr, nullptr, nullptr, nullptr,
        wpG1, gb1, s1, s1 + 128, P1, N, invN);
    // 4) t2 = gelu(bn(t1)) @ gW2 + gb2               -> Zb (no stats)
    gemmf_kernel<128, 128, 2><<<rb, 256, 0, stream>>>(
        P1, s1, s1 + 128, gg, gbb, nullptr, nullptr, nullptr,
        wpG2, gb2, nullptr, nullptr, Zb, N, invN);
    // 5) t3 = t2 @ f2W1 + f2b1                       -> T3, stats s3
    gemmf_kernel<128, 256, 0><<<rb, 256, 0, stream>>>(
        Zb, nullptr, nullptr, nullptr, nullptr, nullptr, nullptr, nullptr,
        wpF1, f2b1, s3, s3 + 256, T3, N, invN);
    // 6) t4 = gelu(bn(t3)) @ f2W2 + f2b2             -> P1, stats s4
    gemmf_kernel<256, 128, 2><<<rb, 256, 0, stream>>>(
        T3, s3, s3 + 256, f2g1, f2bb1, nullptr, nullptr, nullptr,
        wpF2, f2b2, s4, s4 + 128, P1, N, invN);
    // 7) h3 = bn(t4)+t2+x (side-write H3); t5 = h3 @ fnW1 + fnb1 -> T5, stats s5
    gemmf_kernel<128, 512, 3><<<rb, 512, 0, stream>>>(
        P1, s4, s4 + 128, f2g2, f2bb2, Zb, x, H3,
        wpN1, fnb1, s5, s5 + 512, T5, N, invN);
    // 8) t6 = gelu(bn(t5)) @ fnW2 + fnb2             -> P1, stats s6
    gemmf_kernel<512, 128, 2><<<rb, 256, 0, stream>>>(
        T5, s5, s5 + 512, fng1, fnbb1, nullptr, nullptr, nullptr,
        wpN2, fnb2, s6, s6 + 128, P1, N, invN);
    // 9) out = bn(t6) + h3                            -> d_out (fp32)
    final_kernel<<<(t4a + 255) / 256, 256, 0, stream>>>(
        P1, s6, s6 + 128, fng2, fnbb2, H3, (float*)d_out, invN, t4a);

    (void)n_in; (void)out_size; (void)ws_size;
}

// Round 4
// 484.193 us; speedup vs baseline: 3.9238x; 1.1861x over previous
//
#include <hip/hip_runtime.h>
#include <hip/hip_bf16.h>

typedef __attribute__((ext_vector_type(8))) short short8;
typedef __attribute__((ext_vector_type(4))) float f32x4;

__device__ __forceinline__ float bf2f(unsigned short u) {
    union { unsigned int i; float f; } c;
    c.i = ((unsigned int)u) << 16;
    return c.f;
}
__device__ __forceinline__ unsigned short f2bf(float f) {
    union { float f; unsigned int i; } c;
    c.f = f;
    unsigned int x = c.i;
    x += 0x7FFFu + ((x >> 16) & 1u);
    return (unsigned short)(x >> 16);
}

// ---------------- fused GEMM: C[n,M] = f(A)[n,K] @ W[K,M] + bias ------------
// Tile: 64 rows x 128 cols, K-chunk 128. LDS = A(16KB) + B(32KB) = 48KB ->
// 3 blocks/CU, 12 waves/CU. Wide M via blockIdx.y (A re-read per col-tile).
// Frag layout: 1KB/frag; frag-lane j at byte (j*16)^((j>>4)<<5) (XOR kills the
// 4-way staging-write conflict; read side stays ~2-way = free).
// XF: 0=bf16 passthrough, 1=fp32 cast, 2=BN+GELU, 3=BN+res1(bf16)+res2(f32)
// (XF3 side-writes transformed A to h3out once, on blockIdx.y==0).
template<int K, int XF>
__global__ __launch_bounds__(256, 3)
void gemmf_kernel(const void* __restrict__ Av,
                  const float* __restrict__ pSum, const float* __restrict__ pSq,
                  const float* __restrict__ pG, const float* __restrict__ pB,
                  const unsigned short* __restrict__ res1,
                  const float* __restrict__ res2,
                  unsigned short* __restrict__ h3out,
                  const unsigned short* __restrict__ Wp,
                  const float* __restrict__ bias,
                  float* __restrict__ ssum, float* __restrict__ ssq,
                  unsigned short* __restrict__ C,
                  int nrows, int M, float invN)
{
    constexpr int KS  = 4;            // k-steps per chunk (KC=128)
    constexpr int NR  = 4;            // row-blocks (64 rows)
    constexpr int NCW = 2;            // col-blocks per wave (4 waves x 2 x 16 = 128)
    constexpr int NFA = NR * KS;      // 16 A frags
    constexpr int NFB = 8 * KS;       // 32 B frags
    constexpr int NKC = K / 128;
    __shared__ __align__(16) char smem[(NFA + NFB) * 1024];

    const int tid = threadIdx.x;
    const int l   = tid & 63, wv = tid >> 6;
    const int gr0 = blockIdx.x * 64;
    const int gc0 = blockIdx.y * 128;

    const int kq4 = l & 3, rloc = l >> 2;
    const int woff = ((kq4 * 16 + rloc) * 16) ^ (kq4 << 5);   // staging write
    const int loff = (l * 16) ^ ((l >> 4) << 5);              // frag read

    f32x4 acc[NR][NCW];
    #pragma unroll
    for (int r = 0; r < NR; ++r)
        #pragma unroll
        for (int c = 0; c < NCW; ++c) acc[r][c] = f32x4{0.f, 0.f, 0.f, 0.f};

    for (int kc = 0; kc < NKC; ++kc) {
        const int kcb = kc * 128;
        // ---- stage A (transform fused); 4 frag-lanes per thread ----
        #pragma unroll
        for (int i = 0; i < NFA / 4; ++i) {
            const int f = i * 4 + wv;
            const int rowblk = f >> 2, kstep = f & 3;
            int rowg = gr0 + rowblk * 16 + rloc;
            const bool valid = rowg < nrows;
            if (!valid) rowg = nrows - 1;
            const int c0k = kcb + (kstep * 4 + kq4) * 8;
            const size_t eoff = (size_t)rowg * K + c0k;
            short8 val;
            if (XF == 0) {
                val = *(const short8*)((const unsigned short*)Av + eoff);
            } else if (XF == 1) {
                const float* A = (const float*)Av;
                f32x4 u0 = *(const f32x4*)(A + eoff);
                f32x4 u1 = *(const f32x4*)(A + eoff + 4);
                #pragma unroll
                for (int j = 0; j < 4; ++j) {
                    val[j]     = (short)f2bf(u0[j]);
                    val[j + 4] = (short)f2bf(u1[j]);
                }
            } else {
                short8 t = *(const short8*)((const unsigned short*)Av + eoff);
                float o[8];
                #pragma unroll
                for (int j = 0; j < 8; ++j) {
                    const int c = c0k + j;
                    const float mean = pSum[c] * invN;
                    const float var  = pSq[c] * invN - mean * mean;
                    const float sc   = pG[c] * rsqrtf(var + 1e-5f);
                    const float sh   = pB[c] - mean * sc;
                    float v = sc * bf2f((unsigned short)t[j]) + sh;
                    if (XF == 2) v = 0.5f * v * (1.0f + erff(v * 0.70710678118f));
                    o[j] = v;
                }
                if (XF == 3) {
                    short8 r1 = *(const short8*)(res1 + eoff);
                    f32x4 x0 = *(const f32x4*)(res2 + eoff);
                    f32x4 x1 = *(const f32x4*)(res2 + eoff + 4);
                    #pragma unroll
                    for (int j = 0; j < 4; ++j) {
                        o[j]     += bf2f((unsigned short)r1[j])     + x0[j];
                        o[j + 4] += bf2f((unsigned short)r1[j + 4]) + x1[j];
                    }
                }
                #pragma unroll
                for (int j = 0; j < 8; ++j) val[j] = (short)f2bf(o[j]);
                if (XF == 3 && valid && blockIdx.y == 0)
                    *(short8*)(h3out + eoff) = val;
            }
            *(short8*)(smem + f * 1024 + woff) = val;
        }
        // ---- stage B; 8 frag-lanes per thread ----
        #pragma unroll
        for (int i = 0; i < NFB / 4; ++i) {
            const int f = i * 4 + wv;
            const int colblk = f >> 2, kstep = f & 3;
            const int col = gc0 + colblk * 16 + rloc;
            const size_t eoff = (size_t)col * K + kcb + (kstep * 4 + kq4) * 8;
            *(short8*)(smem + (NFA + f) * 1024 + woff) = *(const short8*)(Wp + eoff);
        }
        __syncthreads();
        // ---- MFMA loop, LDS-resident ----
        #pragma unroll
        for (int ks = 0; ks < KS; ++ks) {
            short8 af[NR], bfr[NCW];
            #pragma unroll
            for (int r = 0; r < NR; ++r)
                af[r] = *(const short8*)(smem + (r * KS + ks) * 1024 + loff);
            #pragma unroll
            for (int c = 0; c < NCW; ++c)
                bfr[c] = *(const short8*)(smem + (NFA + (wv * NCW + c) * KS + ks) * 1024 + loff);
            #pragma unroll
            for (int r = 0; r < NR; ++r)
                #pragma unroll
                for (int c = 0; c < NCW; ++c)
                    acc[r][c] = __builtin_amdgcn_mfma_f32_16x16x32_bf16(af[r], bfr[c], acc[r][c], 0, 0, 0);
        }
        if (kc + 1 < NKC) __syncthreads();
    }

    // ---- epilogue: bias, bf16 store, per-column stats ----
    const int lrow = l & 15, kg = l >> 4;
    #pragma unroll
    for (int c = 0; c < NCW; ++c) {
        const int col = gc0 + (wv * NCW + c) * 16 + lrow;
        const float bc = bias[col];
        float s = 0.f, q = 0.f;
        #pragma unroll
        for (int r = 0; r < NR; ++r) {
            const int rb = gr0 + r * 16 + kg * 4;
            #pragma unroll
            for (int i = 0; i < 4; ++i) {
                const int row = rb + i;
                if (row < nrows) {
                    const float v = acc[r][c][i] + bc;
                    C[(size_t)row * M + col] = f2bf(v);
                    s += v; q += v * v;
                }
            }
        }
        s += __shfl_xor(s, 16); s += __shfl_xor(s, 32);
        q += __shfl_xor(q, 16); q += __shfl_xor(q, 32);
        if (kg == 0 && ssum != nullptr) {
            atomicAdd(&ssum[col], s);
            atomicAdd(&ssq[col], q);
        }
    }
}

// ---------------- CSR build ------------------------------------------------
__global__ void hist_kernel(const int* __restrict__ ei, int* __restrict__ cnt, int E)
{
    int e = blockIdx.x * blockDim.x + threadIdx.x;
    if (e < E) atomicAdd(&cnt[ei[E + e]], 1);
}

__global__ void scan_reduce(const int* __restrict__ cnt, int* __restrict__ blksum, int n)
{
    __shared__ int s[256];
    int t = threadIdx.x;
    int i = blockIdx.x * 256 + t;
    s[t] = i < n ? cnt[i] : 0;
    __syncthreads();
    for (int d = 128; d > 0; d >>= 1) {
        if (t < d) s[t] += s[t + d];
        __syncthreads();
    }
    if (t == 0) blksum[blockIdx.x] = s[0];
}

__global__ void scan_top(int* __restrict__ blksum, int nb)
{
    __shared__ int s[256];
    int t = threadIdx.x;
    int v = t < nb ? blksum[t] : 0;
    s[t] = v;
    __syncthreads();
    for (int d = 1; d < 256; d <<= 1) {
        int u = (t >= d) ? s[t - d] : 0;
        __syncthreads();
        s[t] += u;
        __syncthreads();
    }
    if (t < nb) blksum[t] = s[t] - v;   // exclusive
}

__global__ void scan_apply(const int* __restrict__ cnt, const int* __restrict__ blksum,
                           int* __restrict__ offs, int* __restrict__ cursor, int n)
{
    __shared__ int s[256];
    int t = threadIdx.x;
    int i = blockIdx.x * 256 + t;
    int v = i < n ? cnt[i] : 0;
    s[t] = v;
    __syncthreads();
    for (int d = 1; d < 256; d <<= 1) {
        int u = (t >= d) ? s[t - d] : 0;
        __syncthreads();
        s[t] += u;
        __syncthreads();
    }
    int excl = s[t] - v + blksum[blockIdx.x];
    if (i < n) { offs[i] = excl; cursor[i] = excl; }
}

__global__ void place_kernel(const int* __restrict__ ei, int* __restrict__ cursor,
                             int* __restrict__ ssrc, int E)
{
    int e = blockIdx.x * blockDim.x + threadIdx.x;
    if (e < E) {
        int pos = atomicAdd(&cursor[ei[E + e]], 1);
        ssrc[pos] = ei[e];
    }
}

// ---------------- GIN gather with fused BN0 --------------------------------
// Z_i = sc o (t0_i + sum_j t0_j) + (deg_i + 1) * sh   (affine commutes w/ sum)
__global__ __launch_bounds__(256)
void gather_kernel(const unsigned short* __restrict__ T0,
                   const float* __restrict__ pSum, const float* __restrict__ pSq,
                   const float* __restrict__ pG, const float* __restrict__ pB,
                   float invN,
                   const int* __restrict__ ssrc, const int* __restrict__ offs,
                   const int* __restrict__ cnt,
                   unsigned short* __restrict__ Zb, int N)
{
    const int wave = threadIdx.x >> 6;
    const int lane = threadIdx.x & 63;
    const int node = blockIdx.x * 4 + wave;
    if (node >= N) return;

    unsigned int hv = *(const unsigned int*)(T0 + (size_t)node * 128 + lane * 2);
    float a0 = bf2f((unsigned short)hv);
    float a1 = bf2f((unsigned short)(hv >> 16));

    const int off = offs[node];
    const int deg = cnt[node];
    for (int base = 0; base < deg; base += 64) {
        int m = deg - base;
        if (m > 64) m = 64;
        int idx = (base + lane < deg) ? ssrc[off + base + lane] : 0;
        int k = 0;
        for (; k + 1 < m; k += 2) {
            int s0 = __shfl(idx, k);
            int s1 = __shfl(idx, k + 1);
            unsigned int v0 = *(const unsigned int*)(T0 + (size_t)s0 * 128 + lane * 2);
            unsigned int v1 = *(const unsigned int*)(T0 + (size_t)s1 * 128 + lane * 2);
            a0 += bf2f((unsigned short)v0) + bf2f((unsigned short)v1);
            a1 += bf2f((unsigned short)(v0 >> 16)) + bf2f((unsigned short)(v1 >> 16));
        }
        if (k < m) {
            int s0 = __shfl(idx, k);
            unsigned int v0 = *(const unsigned int*)(T0 + (size_t)s0 * 128 + lane * 2);
            a0 += bf2f((unsigned short)v0);
            a1 += bf2f((unsigned short)(v0 >> 16));
        }
    }
    const int c0 = lane * 2;
    const float mean0 = pSum[c0] * invN;
    const float var0  = pSq[c0] * invN - mean0 * mean0;
    const float sc0   = pG[c0] * rsqrtf(var0 + 1e-5f);
    const float sh0   = pB[c0] - mean0 * sc0;
    const float mean1 = pSum[c0 + 1] * invN;
    const float var1  = pSq[c0 + 1] * invN - mean1 * mean1;
    const float sc1   = pG[c0 + 1] * rsqrtf(var1 + 1e-5f);
    const float sh1   = pB[c0 + 1] - mean1 * sc1;
    const float dp1 = (float)(deg + 1);
    const float z0 = sc0 * a0 + dp1 * sh0;
    const float z1 = sc1 * a1 + dp1 * sh1;
    unsigned int o = ((unsigned int)f2bf(z1) << 16) | (unsigned int)f2bf(z0);
    *(unsigned int*)(Zb + (size_t)node * 128 + lane * 2) = o;
}

// ---------------- final: out = bn(t6) + h3 (fp32) --------------------------
__global__ void final_kernel(const unsigned short* __restrict__ t6,
                             const float* __restrict__ pSum, const float* __restrict__ pSq,
                             const float* __restrict__ pG, const float* __restrict__ pB,
                             const unsigned short* __restrict__ h3,
                             float* __restrict__ out, float invN, int total4)
{
    int idx = blockIdx.x * blockDim.x + threadIdx.x;
    if (idx >= total4) return;
    const int base = idx * 4;
    const int c0 = base & 127;
    ushort4 tv = *(const ushort4*)(t6 + base);
    ushort4 hv = *(const ushort4*)(h3 + base);
    unsigned short ts[4] = {tv.x, tv.y, tv.z, tv.w};
    unsigned short hs[4] = {hv.x, hv.y, hv.z, hv.w};
    float4 ov;
    float* po = &ov.x;
    #pragma unroll
    for (int j = 0; j < 4; ++j) {
        const int c = c0 + j;
        const float mean = pSum[c] * invN;
        const float var  = pSq[c] * invN - mean * mean;
        const float sc   = pG[c] * rsqrtf(var + 1e-5f);
        const float sh   = pB[c] - mean * sc;
        po[j] = sc * bf2f(ts[j]) + sh + bf2f(hs[j]);
    }
    *(float4*)(out + base) = ov;
}

// ---------------- weight pack: Wp[m][k] = bf16(W[k][m]) ---------------------
struct PackDesc { const float* src; unsigned short* dst; int K; int M; };
struct Pack7 { PackDesc d[7]; };
__global__ void pack_kernel(Pack7 p)
{
    PackDesc d = p.d[blockIdx.y];
    const int total = d.K * d.M;
    for (int idx = blockIdx.x * blockDim.x + threadIdx.x; idx < total;
         idx += gridDim.x * blockDim.x) {
        const int k = idx / d.M;
        const int m = idx - k * d.M;
        d.dst[(size_t)m * d.K + k] = f2bf(d.src[idx]);
    }
}

extern "C" void kernel_launch(void* const* d_in, const int* in_sizes, int n_in,
                              void* d_out, int out_size, void* d_ws, size_t ws_size,
                              hipStream_t stream)
{
    const float* x     = (const float*)d_in[0];
    const int*   ei    = (const int*)d_in[1];
    const float* enc_W = (const float*)d_in[2];
    const float* enc_b = (const float*)d_in[3];
    const float* bn_g  = (const float*)d_in[4];
    const float* bn_b  = (const float*)d_in[5];
    const float* gW1   = (const float*)d_in[6];
    const float* gb1   = (const float*)d_in[7];
    const float* gg    = (const float*)d_in[8];
    const float* gbb   = (const float*)d_in[9];
    const float* gW2   = (const float*)d_in[10];
    const float* gb2   = (const float*)d_in[11];
    const float* f2W1  = (const float*)d_in[12];
    const float* f2b1  = (const float*)d_in[13];
    const float* f2g1  = (const float*)d_in[14];
    const float* f2bb1 = (const float*)d_in[15];
    const float* f2W2  = (const float*)d_in[16];
    const float* f2b2  = (const float*)d_in[17];
    const float* f2g2  = (const float*)d_in[18];
    const float* f2bb2 = (const float*)d_in[19];
    const float* fnW1  = (const float*)d_in[20];
    const float* fnb1  = (const float*)d_in[21];
    const float* fng1  = (const float*)d_in[22];
    const float* fnbb1 = (const float*)d_in[23];
    const float* fnW2  = (const float*)d_in[24];
    const float* fnb2  = (const float*)d_in[25];
    const float* fng2  = (const float*)d_in[26];
    const float* fnbb2 = (const float*)d_in[27];

    const int D = 128;
    const int N = in_sizes[0] / D;   // 50000
    const int E = in_sizes[1] / 2;   // 640000
    const float invN = 1.0f / (float)N;

    // ---- workspace layout ----
    char* w = (char*)d_ws;
    float* s0 = (float*)w;          // [sum(128) | sq(128)]
    float* s1 = s0 + 256;
    float* s3 = s1 + 256;           // [sum(256) | sq(256)]
    float* s4 = s3 + 512;
    float* s5 = s4 + 256;           // [sum(512) | sq(512)]
    float* s6 = s5 + 1024;
    const size_t statsBytes = 2560 * sizeof(float);
    size_t off = statsBytes;

    unsigned short* wpE  = (unsigned short*)(w + off); off += (size_t)128 * 128 * 2;
    unsigned short* wpG1 = (unsigned short*)(w + off); off += (size_t)128 * 128 * 2;
    unsigned short* wpG2 = (unsigned short*)(w + off); off += (size_t)128 * 128 * 2;
    unsigned short* wpF1 = (unsigned short*)(w + off); off += (size_t)128 * 256 * 2;
    unsigned short* wpF2 = (unsigned short*)(w + off); off += (size_t)256 * 128 * 2;
    unsigned short* wpN1 = (unsigned short*)(w + off); off += (size_t)128 * 512 * 2;
    unsigned short* wpN2 = (unsigned short*)(w + off); off += (size_t)512 * 128 * 2;

    unsigned short* P1 = (unsigned short*)(w + off); off += (size_t)N * 128 * 2; // t0,t1,t4,t6
    unsigned short* Zb = (unsigned short*)(w + off); off += (size_t)N * 128 * 2; // Z, t2
    unsigned short* H3 = (unsigned short*)(w + off); off += (size_t)N * 128 * 2; // h3
    unsigned short* T3 = (unsigned short*)(w + off); off += (size_t)N * 256 * 2; // t3
    unsigned short* T5 = (unsigned short*)(w + off); off += (size_t)N * 512 * 2; // t5

    // CSR arrays inside T5 (CSR dead after gather; T5 first written later)
    const int NB = (N + 255) / 256;
    char* csr = (char*)T5;
    int* cnt    = (int*)csr;  csr += (size_t)NB * 256 * 4;
    int* offs   = (int*)csr;  csr += (size_t)NB * 256 * 4;
    int* cursor = (int*)csr;  csr += (size_t)NB * 256 * 4;
    int* blksum = (int*)csr;  csr += 1024;
    int* ssrc   = (int*)csr;

    hipMemsetAsync(d_ws, 0, statsBytes, stream);
    hipMemsetAsync(cnt, 0, (size_t)NB * 256 * 4, stream);

    Pack7 pk;
    pk.d[0] = PackDesc{enc_W, wpE, 128, 128};
    pk.d[1] = PackDesc{gW1, wpG1, 128, 128};
    pk.d[2] = PackDesc{gW2, wpG2, 128, 128};
    pk.d[3] = PackDesc{f2W1, wpF1, 128, 256};
    pk.d[4] = PackDesc{f2W2, wpF2, 256, 128};
    pk.d[5] = PackDesc{fnW1, wpN1, 128, 512};
    pk.d[6] = PackDesc{fnW2, wpN2, 512, 128};
    pack_kernel<<<dim3(64, 7), 256, 0, stream>>>(pk);

    const int eb = (E + 255) / 256;
    hist_kernel<<<eb, 256, 0, stream>>>(ei, cnt, E);
    scan_reduce<<<NB, 256, 0, stream>>>(cnt, blksum, N);
    scan_top<<<1, 256, 0, stream>>>(blksum, NB);
    scan_apply<<<NB, 256, 0, stream>>>(cnt, blksum, offs, cursor, N);
    place_kernel<<<eb, 256, 0, stream>>>(ei, cursor, ssrc, E);

    const int rb  = (N + 63) / 64;
    const int t4a = N * 128 / 4;

    // 1) t0 = x @ encW + enc_b                       -> P1, stats s0
    gemmf_kernel<128, 1><<<dim3(rb, 1), 256, 0, stream>>>(
        x, nullptr, nullptr, nullptr, nullptr, nullptr, nullptr, nullptr,
        wpE, enc_b, s0, s0 + 128, P1, N, 128, invN);
    // 2) Z = bn0(t0 self+agg)                        -> Zb
    gather_kernel<<<(N + 3) / 4, 256, 0, stream>>>(
        P1, s0, s0 + 128, bn_g, bn_b, invN, ssrc, offs, cnt, Zb, N);
    // 3) t1 = Z @ gW1 + gb1                          -> P1, stats s1
    gemmf_kernel<128, 0><<<dim3(rb, 1), 256, 0, stream>>>(
        Zb, nullptr, nullptr, nullptr, nullptr, nullptr, nullptr, nullptr,
        wpG1, gb1, s1, s1 + 128, P1, N, 128, invN);
    // 4) t2 = gelu(bn(t1)) @ gW2 + gb2               -> Zb (no stats)
    gemmf_kernel<128, 2><<<dim3(rb, 1), 256, 0, stream>>>(
        P1, s1, s1 + 128, gg, gbb, nullptr, nullptr, nullptr,
        wpG2, gb2, nullptr, nullptr, Zb, N, 128, invN);
    // 5) t3 = t2 @ f2W1 + f2b1                       -> T3 [N,256], stats s3
    gemmf_kernel<128, 0><<<dim3(rb, 2), 256, 0, stream>>>(
        Zb, nullptr, nullptr, nullptr, nullptr, nullptr, nullptr, nullptr,
        wpF1, f2b1, s3, s3 + 256, T3, N, 256, invN);
    // 6) t4 = gelu(bn(t3)) @ f2W2 + f2b2             -> P1, stats s4
    gemmf_kernel<256, 2><<<dim3(rb, 1), 256, 0, stream>>>(
        T3, s3, s3 + 256, f2g1, f2bb1, nullptr, nullptr, nullptr,
        wpF2, f2b2, s4, s4 + 128, P1, N, 128, invN);
    // 7) h3 = bn(t4)+t2+x (side-write H3); t5 = h3 @ fnW1 + fnb1 -> T5, stats s5
    gemmf_kernel<128, 3><<<dim3(rb, 4), 256, 0, stream>>>(
        P1, s4, s4 + 128, f2g2, f2bb2, Zb, x, H3,
        wpN1, fnb1, s5, s5 + 512, T5, N, 512, invN);
    // 8) t6 = gelu(bn(t5)) @ fnW2 + fnb2             -> P1, stats s6
    gemmf_kernel<512, 2><<<dim3(rb, 1), 256, 0, stream>>>(
        T5, s5, s5 + 512, fng1, fnbb1, nullptr, nullptr, nullptr,
        wpN2, fnb2, s6, s6 + 128, P1, N, 128, invN);
    // 9) out = bn(t6) + h3                            -> d_out (fp32)
    final_kernel<<<(t4a + 255) / 256, 256, 0, stream>>>(
        P1, s6, s6 + 128, fng2, fnbb2, H3, (float*)d_out, invN, t4a);

    (void)n_in; (void)out_size; (void)ws_size;
}

// Round 5
// 452.008 us; speedup vs baseline: 4.2032x; 1.0712x over previous
//
#include <hip/hip_runtime.h>
#include <hip/hip_bf16.h>

typedef __attribute__((ext_vector_type(8))) short short8;
typedef __attribute__((ext_vector_type(4))) float f32x4;

__device__ __forceinline__ float bf2f(unsigned short u) {
    union { unsigned int i; float f; } c;
    c.i = ((unsigned int)u) << 16;
    return c.f;
}
__device__ __forceinline__ unsigned short f2bf(float f) {
    union { float f; unsigned int i; } c;
    c.f = f;
    unsigned int x = c.i;
    x += 0x7FFFu + ((x >> 16) & 1u);
    return (unsigned short)(x >> 16);
}

// ---------------- fused GEMM: C[n,M] = f(A)[n,K] @ W[K,M] + bias ------------
// Tile 64 rows x 128 cols. A staged in LDS (16KB; x2 buffers for K>128),
// B loaded global->registers (Wp [M][K] is fragment-contiguous, L2-resident).
// K>128: T14 split -- issue next-chunk A loads, MFMA current, then
// transform+ds_write, barrier. XF: 0=bf16 pass, 1=fp32 cast, 2=BN+GELU.
template<int K, int XF>
__global__ __launch_bounds__(256, 4)
void gemmf_kernel(const void* __restrict__ Av,
                  const float* __restrict__ pSum, const float* __restrict__ pSq,
                  const float* __restrict__ pG, const float* __restrict__ pB,
                  const unsigned short* __restrict__ Wp,
                  const float* __restrict__ bias,
                  float* __restrict__ ssum, float* __restrict__ ssq,
                  unsigned short* __restrict__ C,
                  int nrows, int M, float invN)
{
    constexpr int KS  = 4;            // k-steps per 128-chunk
    constexpr int NR  = 4;            // row-blocks (64 rows)
    constexpr int NCW = 2;            // col-blocks per wave
    constexpr int NFA = 16;           // A frags per chunk
    constexpr int NKC = K / 128;
    constexpr int NBUF = (NKC > 1) ? 2 : 1;
    __shared__ __align__(16) char smem[NBUF * NFA * 1024];

    const int tid = threadIdx.x;
    const int l   = tid & 63, wv = tid >> 6;
    const int gr0 = blockIdx.x * 64;
    const int gc0 = blockIdx.y * 128;
    const int kq4 = l & 3, rloc = l >> 2;
    const int woff = ((kq4 * 16 + rloc) * 16) ^ (kq4 << 5);   // staging write (swizzled)
    const int loff = (l * 16) ^ ((l >> 4) << 5);              // frag read (swizzled)
    const int akoff = wv * 32 + kq4 * 8;                      // thread's k-offset in chunk

    f32x4 acc[NR][NCW];
    #pragma unroll
    for (int r = 0; r < NR; ++r)
        #pragma unroll
        for (int c = 0; c < NCW; ++c) acc[r][c] = f32x4{0.f, 0.f, 0.f, 0.f};

    int rowg[NR];
    #pragma unroll
    for (int i = 0; i < NR; ++i) {
        int rg = gr0 + i * 16 + rloc;
        rowg[i] = rg < nrows ? rg : nrows - 1;
    }

    short8 breg[NCW * KS];
    auto loadB = [&](int kcb) {
        #pragma unroll
        for (int c = 0; c < NCW; ++c) {
            const int col = gc0 + (wv * NCW + c) * 16 + (l & 15);
            const unsigned short* bp = Wp + (size_t)col * K + kcb + (l >> 4) * 8;
            #pragma unroll
            for (int ks = 0; ks < KS; ++ks)
                breg[c * KS + ks] = *(const short8*)(bp + ks * 32);
        }
    };

    auto xform = [&](int kcb, short8 t) -> short8 {
        short8 val;
        if (XF == 0) {
            val = t;
        } else {
            #pragma unroll
            for (int j = 0; j < 8; ++j) {
                const int c = kcb + akoff + j;
                const float mean = pSum[c] * invN;
                const float var  = pSq[c] * invN - mean * mean;
                const float sc   = pG[c] * rsqrtf(var + 1e-5f);
                const float sh   = pB[c] - mean * sc;
                float v = sc * bf2f((unsigned short)t[j]) + sh;
                v = 0.5f * v * (1.0f + erff(v * 0.70710678118f));
                val[j] = (short)f2bf(v);
            }
        }
        return val;
    };

    auto domfma = [&](int cur) {
        #pragma unroll
        for (int ks = 0; ks < KS; ++ks) {
            short8 af[NR];
            #pragma unroll
            for (int r = 0; r < NR; ++r)
                af[r] = *(const short8*)(smem + cur * (NFA * 1024) + (r * 4 + ks) * 1024 + loff);
            #pragma unroll
            for (int r = 0; r < NR; ++r)
                #pragma unroll
                for (int c = 0; c < NCW; ++c)
                    acc[r][c] = __builtin_amdgcn_mfma_f32_16x16x32_bf16(af[r], breg[c * KS + ks], acc[r][c], 0, 0, 0);
        }
    };

    if (NKC == 1) {
        loadB(0);
        // direct stage of the single chunk
        #pragma unroll
        for (int i = 0; i < NR; ++i) {
            short8 val;
            if (XF == 1) {
                const float* A = (const float*)Av;
                const float* p = A + (size_t)rowg[i] * K + akoff;
                f32x4 u0 = *(const f32x4*)p;
                f32x4 u1 = *(const f32x4*)(p + 4);
                #pragma unroll
                for (int j = 0; j < 4; ++j) {
                    val[j]     = (short)f2bf(u0[j]);
                    val[j + 4] = (short)f2bf(u1[j]);
                }
            } else {
                short8 t = *(const short8*)((const unsigned short*)Av + (size_t)rowg[i] * K + akoff);
                val = xform(0, t);
            }
            *(short8*)(smem + (i * 4 + wv) * 1024 + woff) = val;
        }
        __syncthreads();
        domfma(0);
    } else {
        // prologue: stage chunk 0
        #pragma unroll
        for (int i = 0; i < NR; ++i) {
            short8 t = *(const short8*)((const unsigned short*)Av + (size_t)rowg[i] * K + akoff);
            *(short8*)(smem + (i * 4 + wv) * 1024 + woff) = xform(0, t);
        }
        __syncthreads();
        #pragma unroll
        for (int kc = 0; kc < NKC; ++kc) {
            const int cur = kc & 1;
            loadB(kc * 128);
            short8 anext[NR];
            if (kc + 1 < NKC) {
                const int kcb = (kc + 1) * 128;
                #pragma unroll
                for (int i = 0; i < NR; ++i)
                    anext[i] = *(const short8*)((const unsigned short*)Av + (size_t)rowg[i] * K + kcb + akoff);
            }
            domfma(cur);
            if (kc + 1 < NKC) {
                const int kcb = (kc + 1) * 128;
                #pragma unroll
                for (int i = 0; i < NR; ++i)
                    *(short8*)(smem + (cur ^ 1) * (NFA * 1024) + (i * 4 + wv) * 1024 + woff) = xform(kcb, anext[i]);
                __syncthreads();
            }
        }
    }

    // ---- epilogue: bias, bf16 store, per-column stats ----
    const int lrow = l & 15, kg = l >> 4;
    #pragma unroll
    for (int c = 0; c < NCW; ++c) {
        const int col = gc0 + (wv * NCW + c) * 16 + lrow;
        const float bc = bias[col];
        float s = 0.f, q = 0.f;
        #pragma unroll
        for (int r = 0; r < NR; ++r) {
            const int rb = gr0 + r * 16 + kg * 4;
            #pragma unroll
            for (int i = 0; i < 4; ++i) {
                const int row = rb + i;
                if (row < nrows) {
                    const float v = acc[r][c][i] + bc;
                    C[(size_t)row * M + col] = f2bf(v);
                    s += v; q += v * v;
                }
            }
        }
        s += __shfl_xor(s, 16); s += __shfl_xor(s, 32);
        q += __shfl_xor(q, 16); q += __shfl_xor(q, 32);
        if (kg == 0 && ssum != nullptr) {
            atomicAdd(&ssum[col], s);
            atomicAdd(&ssq[col], q);
        }
    }
}

// ---------------- h3 = bn(t4) + t2 + x (bf16) -------------------------------
__global__ void h3_kernel(const unsigned short* __restrict__ t4,
                          const float* __restrict__ pSum, const float* __restrict__ pSq,
                          const float* __restrict__ pG, const float* __restrict__ pB,
                          const unsigned short* __restrict__ t2,
                          const float* __restrict__ xr,
                          unsigned short* __restrict__ H3, float invN, int total4)
{
    int idx = blockIdx.x * blockDim.x + threadIdx.x;
    if (idx >= total4) return;
    const int base = idx * 4;
    const int c0 = base & 127;
    ushort4 tv = *(const ushort4*)(t4 + base);
    ushort4 uv = *(const ushort4*)(t2 + base);
    float4  xv = *(const float4*)(xr + base);
    unsigned short ts[4] = {tv.x, tv.y, tv.z, tv.w};
    unsigned short us[4] = {uv.x, uv.y, uv.z, uv.w};
    const float* px = &xv.x;
    ushort4 ov;
    unsigned short* po = &ov.x;
    #pragma unroll
    for (int j = 0; j < 4; ++j) {
        const int c = c0 + j;
        const float mean = pSum[c] * invN;
        const float var  = pSq[c] * invN - mean * mean;
        const float sc   = pG[c] * rsqrtf(var + 1e-5f);
        const float sh   = pB[c] - mean * sc;
        po[j] = f2bf(sc * bf2f(ts[j]) + sh + bf2f(us[j]) + px[j]);
    }
    *(ushort4*)(H3 + base) = ov;
}

// ---------------- CSR build ------------------------------------------------
__global__ void hist_kernel(const int* __restrict__ ei, int* __restrict__ cnt, int E)
{
    int e = blockIdx.x * blockDim.x + threadIdx.x;
    if (e < E) atomicAdd(&cnt[ei[E + e]], 1);
}

__global__ void scan_reduce(const int* __restrict__ cnt, int* __restrict__ blksum, int n)
{
    __shared__ int s[256];
    int t = threadIdx.x;
    int i = blockIdx.x * 256 + t;
    s[t] = i < n ? cnt[i] : 0;
    __syncthreads();
    for (int d = 128; d > 0; d >>= 1) {
        if (t < d) s[t] += s[t + d];
        __syncthreads();
    }
    if (t == 0) blksum[blockIdx.x] = s[0];
}

__global__ void scan_top(int* __restrict__ blksum, int nb)
{
    __shared__ int s[256];
    int t = threadIdx.x;
    int v = t < nb ? blksum[t] : 0;
    s[t] = v;
    __syncthreads();
    for (int d = 1; d < 256; d <<= 1) {
        int u = (t >= d) ? s[t - d] : 0;
        __syncthreads();
        s[t] += u;
        __syncthreads();
    }
    if (t < nb) blksum[t] = s[t] - v;   // exclusive
}

__global__ void scan_apply(const int* __restrict__ cnt, const int* __restrict__ blksum,
                           int* __restrict__ offs, int* __restrict__ cursor, int n)
{
    __shared__ int s[256];
    int t = threadIdx.x;
    int i = blockIdx.x * 256 + t;
    int v = i < n ? cnt[i] : 0;
    s[t] = v;
    __syncthreads();
    for (int d = 1; d < 256; d <<= 1) {
        int u = (t >= d) ? s[t - d] : 0;
        __syncthreads();
        s[t] += u;
        __syncthreads();
    }
    int excl = s[t] - v + blksum[blockIdx.x];
    if (i < n) { offs[i] = excl; cursor[i] = excl; }
}

__global__ void place_kernel(const int* __restrict__ ei, int* __restrict__ cursor,
                             int* __restrict__ ssrc, int E)
{
    int e = blockIdx.x * blockDim.x + threadIdx.x;
    if (e < E) {
        int pos = atomicAdd(&cursor[ei[E + e]], 1);
        ssrc[pos] = ei[e];
    }
}

// ---------------- GIN gather with fused BN0 --------------------------------
__global__ __launch_bounds__(256)
void gather_kernel(const unsigned short* __restrict__ T0,
                   const float* __restrict__ pSum, const float* __restrict__ pSq,
                   const float* __restrict__ pG, const float* __restrict__ pB,
                   float invN,
                   const int* __restrict__ ssrc, const int* __restrict__ offs,
                   const int* __restrict__ cnt,
                   unsigned short* __restrict__ Zb, int N)
{
    const int wave = threadIdx.x >> 6;
    const int lane = threadIdx.x & 63;
    const int node = blockIdx.x * 4 + wave;
    if (node >= N) return;

    unsigned int hv = *(const unsigned int*)(T0 + (size_t)node * 128 + lane * 2);
    float a0 = bf2f((unsigned short)hv);
    float a1 = bf2f((unsigned short)(hv >> 16));

    const int off = offs[node];
    const int deg = cnt[node];
    for (int base = 0; base < deg; base += 64) {
        int m = deg - base;
        if (m > 64) m = 64;
        int idx = (base + lane < deg) ? ssrc[off + base + lane] : 0;
        int k = 0;
        for (; k + 1 < m; k += 2) {
            int s0 = __shfl(idx, k);
            int s1 = __shfl(idx, k + 1);
            unsigned int v0 = *(const unsigned int*)(T0 + (size_t)s0 * 128 + lane * 2);
            unsigned int v1 = *(const unsigned int*)(T0 + (size_t)s1 * 128 + lane * 2);
            a0 += bf2f((unsigned short)v0) + bf2f((unsigned short)v1);
            a1 += bf2f((unsigned short)(v0 >> 16)) + bf2f((unsigned short)(v1 >> 16));
        }
        if (k < m) {
            int s0 = __shfl(idx, k);
            unsigned int v0 = *(const unsigned int*)(T0 + (size_t)s0 * 128 + lane * 2);
            a0 += bf2f((unsigned short)v0);
            a1 += bf2f((unsigned short)(v0 >> 16));
        }
    }
    const int c0 = lane * 2;
    const float mean0 = pSum[c0] * invN;
    const float var0  = pSq[c0] * invN - mean0 * mean0;
    const float sc0   = pG[c0] * rsqrtf(var0 + 1e-5f);
    const float sh0   = pB[c0] - mean0 * sc0;
    const float mean1 = pSum[c0 + 1] * invN;
    const float var1  = pSq[c0 + 1] * invN - mean1 * mean1;
    const float sc1   = pG[c0 + 1] * rsqrtf(var1 + 1e-5f);
    const float sh1   = pB[c0 + 1] - mean1 * sc1;
    const float dp1 = (float)(deg + 1);
    const float z0 = sc0 * a0 + dp1 * sh0;
    const float z1 = sc1 * a1 + dp1 * sh1;
    unsigned int o = ((unsigned int)f2bf(z1) << 16) | (unsigned int)f2bf(z0);
    *(unsigned int*)(Zb + (size_t)node * 128 + lane * 2) = o;
}

// ---------------- final: out = bn(t6) + h3 (fp32) --------------------------
__global__ void final_kernel(const unsigned short* __restrict__ t6,
                             const float* __restrict__ pSum, const float* __restrict__ pSq,
                             const float* __restrict__ pG, const float* __restrict__ pB,
                             const unsigned short* __restrict__ h3,
                             float* __restrict__ out, float invN, int total4)
{
    int idx = blockIdx.x * blockDim.x + threadIdx.x;
    if (idx >= total4) return;
    const int base = idx * 4;
    const int c0 = base & 127;
    ushort4 tv = *(const ushort4*)(t6 + base);
    ushort4 hv = *(const ushort4*)(h3 + base);
    unsigned short ts[4] = {tv.x, tv.y, tv.z, tv.w};
    unsigned short hs[4] = {hv.x, hv.y, hv.z, hv.w};
    float4 ov;
    float* po = &ov.x;
    #pragma unroll
    for (int j = 0; j < 4; ++j) {
        const int c = c0 + j;
        const float mean = pSum[c] * invN;
        const float var  = pSq[c] * invN - mean * mean;
        const float sc   = pG[c] * rsqrtf(var + 1e-5f);
        const float sh   = pB[c] - mean * sc;
        po[j] = sc * bf2f(ts[j]) + sh + bf2f(hs[j]);
    }
    *(float4*)(out + base) = ov;
}

// ---------------- weight pack: Wp[m][k] = bf16(W[k][m]) ---------------------
struct PackDesc { const float* src; unsigned short* dst; int K; int M; };
struct Pack7 { PackDesc d[7]; };
__global__ void pack_kernel(Pack7 p)
{
    PackDesc d = p.d[blockIdx.y];
    const int total = d.K * d.M;
    for (int idx = blockIdx.x * blockDim.x + threadIdx.x; idx < total;
         idx += gridDim.x * blockDim.x) {
        const int k = idx / d.M;
        const int m = idx - k * d.M;
        d.dst[(size_t)m * d.K + k] = f2bf(d.src[idx]);
    }
}

extern "C" void kernel_launch(void* const* d_in, const int* in_sizes, int n_in,
                              void* d_out, int out_size, void* d_ws, size_t ws_size,
                              hipStream_t stream)
{
    const float* x     = (const float*)d_in[0];
    const int*   ei    = (const int*)d_in[1];
    const float* enc_W = (const float*)d_in[2];
    const float* enc_b = (const float*)d_in[3];
    const float* bn_g  = (const float*)d_in[4];
    const float* bn_b  = (const float*)d_in[5];
    const float* gW1   = (const float*)d_in[6];
    const float* gb1   = (const float*)d_in[7];
    const float* gg    = (const float*)d_in[8];
    const float* gbb   = (const float*)d_in[9];
    const float* gW2   = (const float*)d_in[10];
    const float* gb2   = (const float*)d_in[11];
    const float* f2W1  = (const float*)d_in[12];
    const float* f2b1  = (const float*)d_in[13];
    const float* f2g1  = (const float*)d_in[14];
    const float* f2bb1 = (const float*)d_in[15];
    const float* f2W2  = (const float*)d_in[16];
    const float* f2b2  = (const float*)d_in[17];
    const float* f2g2  = (const float*)d_in[18];
    const float* f2bb2 = (const float*)d_in[19];
    const float* fnW1  = (const float*)d_in[20];
    const float* fnb1  = (const float*)d_in[21];
    const float* fng1  = (const float*)d_in[22];
    const float* fnbb1 = (const float*)d_in[23];
    const float* fnW2  = (const float*)d_in[24];
    const float* fnb2  = (const float*)d_in[25];
    const float* fng2  = (const float*)d_in[26];
    const float* fnbb2 = (const float*)d_in[27];

    const int D = 128;
    const int N = in_sizes[0] / D;   // 50000
    const int E = in_sizes[1] / 2;   // 640000
    const float invN = 1.0f / (float)N;

    // ---- workspace layout ----
    char* w = (char*)d_ws;
    float* s0 = (float*)w;          // [sum(128) | sq(128)]
    float* s1 = s0 + 256;
    float* s3 = s1 + 256;           // [sum(256) | sq(256)]
    float* s4 = s3 + 512;
    float* s5 = s4 + 256;           // [sum(512) | sq(512)]
    float* s6 = s5 + 1024;
    const size_t statsBytes = 2560 * sizeof(float);
    size_t off = statsBytes;

    unsigned short* wpE  = (unsigned short*)(w + off); off += (size_t)128 * 128 * 2;
    unsigned short* wpG1 = (unsigned short*)(w + off); off += (size_t)128 * 128 * 2;
    unsigned short* wpG2 = (unsigned short*)(w + off); off += (size_t)128 * 128 * 2;
    unsigned short* wpF1 = (unsigned short*)(w + off); off += (size_t)128 * 256 * 2;
    unsigned short* wpF2 = (unsigned short*)(w + off); off += (size_t)256 * 128 * 2;
    unsigned short* wpN1 = (unsigned short*)(w + off); off += (size_t)128 * 512 * 2;
    unsigned short* wpN2 = (unsigned short*)(w + off); off += (size_t)512 * 128 * 2;

    unsigned short* P1 = (unsigned short*)(w + off); off += (size_t)N * 128 * 2; // t0,t1,t4,t6
    unsigned short* Zb = (unsigned short*)(w + off); off += (size_t)N * 128 * 2; // Z, t2
    unsigned short* H3 = (unsigned short*)(w + off); off += (size_t)N * 128 * 2; // h3
    unsigned short* T3 = (unsigned short*)(w + off); off += (size_t)N * 256 * 2; // t3
    unsigned short* T5 = (unsigned short*)(w + off); off += (size_t)N * 512 * 2; // t5

    // CSR arrays inside T5 (CSR dead after gather; T5 first written later)
    const int NB = (N + 255) / 256;
    char* csr = (char*)T5;
    int* cnt    = (int*)csr;  csr += (size_t)NB * 256 * 4;
    int* offs   = (int*)csr;  csr += (size_t)NB * 256 * 4;
    int* cursor = (int*)csr;  csr += (size_t)NB * 256 * 4;
    int* blksum = (int*)csr;  csr += 1024;
    int* ssrc   = (int*)csr;

    hipMemsetAsync(d_ws, 0, statsBytes, stream);
    hipMemsetAsync(cnt, 0, (size_t)NB * 256 * 4, stream);

    Pack7 pk;
    pk.d[0] = PackDesc{enc_W, wpE, 128, 128};
    pk.d[1] = PackDesc{gW1, wpG1, 128, 128};
    pk.d[2] = PackDesc{gW2, wpG2, 128, 128};
    pk.d[3] = PackDesc{f2W1, wpF1, 128, 256};
    pk.d[4] = PackDesc{f2W2, wpF2, 256, 128};
    pk.d[5] = PackDesc{fnW1, wpN1, 128, 512};
    pk.d[6] = PackDesc{fnW2, wpN2, 512, 128};
    pack_kernel<<<dim3(64, 7), 256, 0, stream>>>(pk);

    const int eb = (E + 255) / 256;
    hist_kernel<<<eb, 256, 0, stream>>>(ei, cnt, E);
    scan_reduce<<<NB, 256, 0, stream>>>(cnt, blksum, N);
    scan_top<<<1, 256, 0, stream>>>(blksum, NB);
    scan_apply<<<NB, 256, 0, stream>>>(cnt, blksum, offs, cursor, N);
    place_kernel<<<eb, 256, 0, stream>>>(ei, cursor, ssrc, E);

    const int rb  = (N + 63) / 64;
    const int t4a = N * 128 / 4;
    const int ewb = (t4a + 255) / 256;

    // 1) t0 = x @ encW + enc_b                       -> P1, stats s0
    gemmf_kernel<128, 1><<<dim3(rb, 1), 256, 0, stream>>>(
        x, nullptr, nullptr, nullptr, nullptr,
        wpE, enc_b, s0, s0 + 128, P1, N, 128, invN);
    // 2) Z = bn0(t0 self+agg)                        -> Zb
    gather_kernel<<<(N + 3) / 4, 256, 0, stream>>>(
        P1, s0, s0 + 128, bn_g, bn_b, invN, ssrc, offs, cnt, Zb, N);
    // 3) t1 = Z @ gW1 + gb1                          -> P1, stats s1
    gemmf_kernel<128, 0><<<dim3(rb, 1), 256, 0, stream>>>(
        Zb, nullptr, nullptr, nullptr, nullptr,
        wpG1, gb1, s1, s1 + 128, P1, N, 128, invN);
    // 4) t2 = gelu(bn(t1)) @ gW2 + gb2               -> Zb (no stats)
    gemmf_kernel<128, 2><<<dim3(rb, 1), 256, 0, stream>>>(
        P1, s1, s1 + 128, gg, gbb,
        wpG2, gb2, nullptr, nullptr, Zb, N, 128, invN);
    // 5) t3 = t2 @ f2W1 + f2b1                       -> T3 [N,256], stats s3
    gemmf_kernel<128, 0><<<dim3(rb, 2), 256, 0, stream>>>(
        Zb, nullptr, nullptr, nullptr, nullptr,
        wpF1, f2b1, s3, s3 + 256, T3, N, 256, invN);
    // 6) t4 = gelu(bn(t3)) @ f2W2 + f2b2             -> P1, stats s4
    gemmf_kernel<256, 2><<<dim3(rb, 1), 256, 0, stream>>>(
        T3, s3, s3 + 256, f2g1, f2bb1,
        wpF2, f2b2, s4, s4 + 128, P1, N, 128, invN);
    // 7) h3 = bn(t4) + t2 + x                        -> H3 (bf16, once)
    h3_kernel<<<ewb, 256, 0, stream>>>(
        P1, s4, s4 + 128, f2g2, f2bb2, Zb, x, H3, invN, t4a);
    // 8) t5 = h3 @ fnW1 + fnb1                       -> T5 [N,512], stats s5
    gemmf_kernel<128, 0><<<dim3(rb, 4), 256, 0, stream>>>(
        H3, nullptr, nullptr, nullptr, nullptr,
        wpN1, fnb1, s5, s5 + 512, T5, N, 512, invN);
    // 9) t6 = gelu(bn(t5)) @ fnW2 + fnb2             -> P1, stats s6
    gemmf_kernel<512, 2><<<dim3(rb, 1), 256, 0, stream>>>(
        T5, s5, s5 + 512, fng1, fnbb1,
        wpN2, fnb2, s6, s6 + 128, P1, N, 128, invN);
    // 10) out = bn(t6) + h3                           -> d_out (fp32)
    final_kernel<<<ewb, 256, 0, stream>>>(
        P1, s6, s6 + 128, fng2, fnbb2, H3, (float*)d_out, invN, t4a);

    (void)n_in; (void)out_size; (void)ws_size;
}